// Round 1
// baseline (1308.370 us; speedup 1.0000x reference)
//
#include <hip/hip_runtime.h>
#include <hip/hip_bf16.h>

using bf16x8  = __attribute__((ext_vector_type(8))) __bf16;
using floatx4 = __attribute__((ext_vector_type(4))) float;

#define DEVINL __device__ __forceinline__

DEVINL void gload16(const void* g, void* l) {
  __builtin_amdgcn_global_load_lds(
      (__attribute__((address_space(1))) void*)g,
      (__attribute__((address_space(3))) void*)l,
      16, 0, 0);
}

constexpr int S_ = 1024, D_ = 4096, HQ_ = 32, HKV_ = 8, HD_ = 128, B_ = 4;

// ---------------- convert x: fp32 -> bf16 ----------------
__global__ void conv_bf16(const float* __restrict__ in, __bf16* __restrict__ out, int n) {
  int i = (blockIdx.x * 256 + threadIdx.x) * 8;
  if (i >= n) return;
  float4 a = *(const float4*)(in + i);
  float4 b = *(const float4*)(in + i + 4);
  bf16x8 o;
  o[0] = (__bf16)a.x; o[1] = (__bf16)a.y; o[2] = (__bf16)a.z; o[3] = (__bf16)a.w;
  o[4] = (__bf16)b.x; o[5] = (__bf16)b.y; o[6] = (__bf16)b.z; o[7] = (__bf16)b.w;
  *(bf16x8*)(out + i) = o;
}

// ---------------- transpose+convert weights: W[K][N] fp32 -> WT[N][K] bf16 ----------------
__global__ void conv_transpose(const float* __restrict__ W, __bf16* __restrict__ WT, int K, int N) {
  __shared__ float tile[32][33];
  int n0 = blockIdx.x * 32, k0 = blockIdx.y * 32;
  int tx = threadIdx.x & 31, ty = threadIdx.x >> 5; // ty 0..7
#pragma unroll
  for (int i = 0; i < 32; i += 8)
    tile[ty + i][tx] = W[(size_t)(k0 + ty + i) * N + n0 + tx];
  __syncthreads();
#pragma unroll
  for (int i = 0; i < 32; i += 8)
    WT[(size_t)(n0 + ty + i) * K + k0 + tx] = (__bf16)tile[tx][ty + i];
}

// ---------------- GEMM: C = A(MxK,bf16) * BT(NxK,bf16)^T + bias ----------------
// MODE 0: plain fp32 out [M][N]
// MODE 1: bf16 out permuted (b,h,s,d):  [b][HH][1024][128]
// MODE 2: bf16 out permuted (b,h,d,s):  [b][HH][128][1024]   (V^T)
template<int MODE, int HH>
__global__ __launch_bounds__(256, 2)
void gemm_bt(const __bf16* __restrict__ A, const __bf16* __restrict__ BT,
             const float* __restrict__ bias, void* __restrict__ Cout,
             int M, int N, int K)
{
  // LDS layout: chunk index (kgroup*128 + row), 8 bf16 per chunk; linear for global_load_lds
  __shared__ __bf16 Alds[4096];
  __shared__ __bf16 Blds[4096];
  const int t = threadIdx.x;
  const int lane = t & 63;
  const int w = t >> 6;
  const int wr = w >> 1, wc = w & 1;
  const int g = lane >> 4, c = lane & 15;
  const int m0 = blockIdx.y * 128, n0 = blockIdx.x * 128;

  const floatx4 zero4 = {0.f, 0.f, 0.f, 0.f};
  floatx4 acc[4][4];
#pragma unroll
  for (int i = 0; i < 4; i++)
#pragma unroll
    for (int j = 0; j < 4; j++) acc[i][j] = zero4;

  const int row = t & 127, kg = t >> 7;   // staging: this thread stages chunks t and t+256
  const __bf16* Ar = A  + (size_t)(m0 + row) * K + kg * 8;
  const __bf16* Br = BT + (size_t)(n0 + row) * K + kg * 8;

  for (int kt = 0; kt < K; kt += 32) {
    gload16(Ar + kt,      &Alds[t * 8]);
    gload16(Ar + kt + 16, &Alds[(t + 256) * 8]);
    gload16(Br + kt,      &Blds[t * 8]);
    gload16(Br + kt + 16, &Blds[(t + 256) * 8]);
    __syncthreads();
    bf16x8 af[4], bf[4];
#pragma unroll
    for (int i = 0; i < 4; i++)
      af[i] = *(const bf16x8*)&Alds[(g * 128 + wr * 64 + i * 16 + c) * 8];
#pragma unroll
    for (int j = 0; j < 4; j++)
      bf[j] = *(const bf16x8*)&Blds[(g * 128 + wc * 64 + j * 16 + c) * 8];
#pragma unroll
    for (int i = 0; i < 4; i++)
#pragma unroll
      for (int j = 0; j < 4; j++)
        acc[i][j] = __builtin_amdgcn_mfma_f32_16x16x32_bf16(af[i], bf[j], acc[i][j], 0, 0, 0);
    __syncthreads();
  }

#pragma unroll
  for (int j = 0; j < 4; j++) {
    const int ncol = n0 + wc * 64 + j * 16 + c;
    const float bv = bias[ncol];
#pragma unroll
    for (int i = 0; i < 4; i++) {
      const int mbase = m0 + wr * 64 + i * 16 + g * 4;
#pragma unroll
      for (int r = 0; r < 4; r++) {
        const int m = mbase + r;
        const float v = acc[i][j][r] + bv;
        if constexpr (MODE == 0) {
          ((float*)Cout)[(size_t)m * N + ncol] = v;
        } else if constexpr (MODE == 1) {
          const int bb = m >> 10, s = m & 1023, hh = ncol >> 7, dd = ncol & 127;
          ((__bf16*)Cout)[(((size_t)bb * HH + hh) * 1024 + s) * 128 + dd] = (__bf16)v;
        } else {
          const int bb = m >> 10, s = m & 1023, hh = ncol >> 7, dd = ncol & 127;
          ((__bf16*)Cout)[(((size_t)bb * HH + hh) * 128 + dd) * 1024 + s] = (__bf16)v;
        }
      }
    }
  }
}

// ---------------- RoPE in-place on q_t (b,h,s,d) and k_t ----------------
constexpr int NQCH = B_ * HQ_ * S_ * (HD_ / 8);   // 2097152 chunks of 8
constexpr int NKCH = B_ * HKV_ * S_ * (HD_ / 8);  //  524288
__global__ void rope_kernel(__bf16* __restrict__ qt, __bf16* __restrict__ kt,
                            const float* __restrict__ fc, const int* __restrict__ sp) {
  int tid = blockIdx.x * 256 + threadIdx.x;
  __bf16* p;
  int idx;
  if (tid < NQCH) { p = qt; idx = tid; }
  else { idx = tid - NQCH; if (idx >= NKCH) return; p = kt; }
  const int c8 = idx & 15;             // 8-elem chunk within d
  const int s  = (idx >> 4) & 1023;
  const int srow = sp[0] + s;
  const float* f = fc + (size_t)srow * 128 + c8 * 8;  // 4 pairs of (cos,sin)
  float4 fa = *(const float4*)(f);
  float4 fb = *(const float4*)(f + 4);
  __bf16* q = p + (size_t)idx * 8;
  bf16x8 v = *(const bf16x8*)q;
  float a0 = (float)v[0], b0 = (float)v[1], a1 = (float)v[2], b1 = (float)v[3];
  float a2 = (float)v[4], b2 = (float)v[5], a3 = (float)v[6], b3 = (float)v[7];
  bf16x8 o;
  o[0] = (__bf16)(a0 * fa.x - b0 * fa.y); o[1] = (__bf16)(a0 * fa.y + b0 * fa.x);
  o[2] = (__bf16)(a1 * fa.z - b1 * fa.w); o[3] = (__bf16)(a1 * fa.w + b1 * fa.z);
  o[4] = (__bf16)(a2 * fb.x - b2 * fb.y); o[5] = (__bf16)(a2 * fb.y + b2 * fb.x);
  o[6] = (__bf16)(a3 * fb.z - b3 * fb.w); o[7] = (__bf16)(a3 * fb.w + b3 * fb.z);
  *(bf16x8*)q = o;
}

// ---------------- flash attention (causal, GQA) ----------------
// grid: (b*HQ + h)*16 + qtile ; 4 waves, wave w owns q-rows [qtile*64 + w*16, +16)
__global__ __launch_bounds__(256, 2)
void flash_attn(const __bf16* __restrict__ qt, const __bf16* __restrict__ kt,
                const __bf16* __restrict__ vt, __bf16* __restrict__ obuf)
{
  __shared__ __bf16 Plds[4][512];  // per-wave 16x32 P tile
  const int lane = threadIdx.x & 63, w = threadIdx.x >> 6;
  const int g = lane >> 4, c = lane & 15;
  const int qtile = blockIdx.x & 15;
  const int bh = blockIdx.x >> 4;
  const int b = bh >> 5, h = bh & 31, hk = h >> 2;
  const int q0 = qtile * 64 + w * 16;
  const __bf16* Q  = qt + (size_t)(b * HQ_ + h) * S_ * HD_;
  const __bf16* Kp = kt + (size_t)(b * HKV_ + hk) * S_ * HD_;
  const __bf16* Vp = vt + (size_t)(b * HKV_ + hk) * HD_ * S_;  // V^T [d][s]

  bf16x8 qa[4];
#pragma unroll
  for (int kc = 0; kc < 4; kc++)
    qa[kc] = *(const bf16x8*)(Q + (size_t)(q0 + c) * HD_ + kc * 32 + g * 8);

  float mr[4], lr[4];
  const floatx4 zero4 = {0.f, 0.f, 0.f, 0.f};
  floatx4 oa[8];
#pragma unroll
  for (int r = 0; r < 4; r++) { mr[r] = -__builtin_inff(); lr[r] = 0.f; }
#pragma unroll
  for (int f = 0; f < 8; f++) oa[f] = zero4;

  const float ksc = 0.12751744875895f;  // (1/sqrt(128)) * log2(e)
  const int kv_end = q0 + 16;
  for (int kv0 = 0; kv0 < kv_end; kv0 += 32) {
    floatx4 s0 = zero4, s1 = zero4;
#pragma unroll
    for (int kc = 0; kc < 4; kc++) {
      bf16x8 k0 = *(const bf16x8*)(Kp + (size_t)(kv0 + c) * HD_ + kc * 32 + g * 8);
      bf16x8 k1 = *(const bf16x8*)(Kp + (size_t)(kv0 + 16 + c) * HD_ + kc * 32 + g * 8);
      s0 = __builtin_amdgcn_mfma_f32_16x16x32_bf16(qa[kc], k0, s0, 0, 0, 0);
      s1 = __builtin_amdgcn_mfma_f32_16x16x32_bf16(qa[kc], k1, s1, 0, 0, 0);
    }
    float p0[4], p1[4];
    const bool need_mask = (kv0 + 31 > q0);
#pragma unroll
    for (int r = 0; r < 4; r++) {
      float a = s0[r] * ksc, bb = s1[r] * ksc;
      if (need_mask) {
        const int q = q0 + g * 4 + r;
        if (kv0 + c > q)      a  = -1e30f;
        if (kv0 + 16 + c > q) bb = -1e30f;
      }
      p0[r] = a; p1[r] = bb;
    }
    float pm[4];
#pragma unroll
    for (int r = 0; r < 4; r++) pm[r] = fmaxf(p0[r], p1[r]);
#pragma unroll
    for (int off = 8; off >= 1; off >>= 1)
#pragma unroll
      for (int r = 0; r < 4; r++) pm[r] = fmaxf(pm[r], __shfl_xor(pm[r], off));
    float al[4], rs[4];
#pragma unroll
    for (int r = 0; r < 4; r++) {
      const float mn = fmaxf(mr[r], pm[r]);
      al[r] = exp2f(mr[r] - mn);
      mr[r] = mn;
      p0[r] = exp2f(p0[r] - mn);
      p1[r] = exp2f(p1[r] - mn);
      rs[r] = p0[r] + p1[r];
    }
#pragma unroll
    for (int off = 8; off >= 1; off >>= 1)
#pragma unroll
      for (int r = 0; r < 4; r++) rs[r] += __shfl_xor(rs[r], off);
#pragma unroll
    for (int r = 0; r < 4; r++) lr[r] = lr[r] * al[r] + rs[r];
#pragma unroll
    for (int f = 0; f < 8; f++)
#pragma unroll
      for (int r = 0; r < 4; r++) oa[f][r] *= al[r];

    __bf16* P = Plds[w];
#pragma unroll
    for (int r = 0; r < 4; r++) {
      P[(g * 4 + r) * 32 + c]      = (__bf16)p0[r];
      P[(g * 4 + r) * 32 + 16 + c] = (__bf16)p1[r];
    }
    bf16x8 pa = *(const bf16x8*)&P[c * 32 + g * 8];
#pragma unroll
    for (int f = 0; f < 8; f++) {
      bf16x8 vb = *(const bf16x8*)(Vp + (size_t)(f * 16 + c) * S_ + kv0 + g * 8);
      oa[f] = __builtin_amdgcn_mfma_f32_16x16x32_bf16(pa, vb, oa[f], 0, 0, 0);
    }
  }

  float inv[4];
#pragma unroll
  for (int r = 0; r < 4; r++) inv[r] = 1.f / lr[r];
#pragma unroll
  for (int f = 0; f < 8; f++)
#pragma unroll
    for (int r = 0; r < 4; r++) {
      const size_t o = (size_t)(b * S_ + q0 + g * 4 + r) * D_ + h * HD_ + f * 16 + c;
      obuf[o] = (__bf16)(oa[f][r] * inv[r]);
    }
}

extern "C" void kernel_launch(void* const* d_in, const int* in_sizes, int n_in,
                              void* d_out, int out_size, void* d_ws, size_t ws_size,
                              hipStream_t stream) {
  (void)in_sizes; (void)n_in; (void)out_size;
  const float* x  = (const float*)d_in[0];
  const float* fc = (const float*)d_in[1];
  const float* Wq = (const float*)d_in[2];
  const float* bq = (const float*)d_in[3];
  const float* Wk = (const float*)d_in[4];
  const float* bk = (const float*)d_in[5];
  const float* Wv = (const float*)d_in[6];
  const float* bv = (const float*)d_in[7];
  const float* Wo = (const float*)d_in[8];
  const float* bo = (const float*)d_in[9];
  const int*   sp = (const int*)d_in[10];
  float* out = (float*)d_out;

  const size_t MB = 1024 * 1024;
  if (ws_size < 192 * MB) return;  // need 192 MB of scratch
  char* ws = (char*)d_ws;
  __bf16* xb  = (__bf16*)(ws + 0);
  __bf16* WqT = (__bf16*)(ws + 32 * MB);
  __bf16* WkT = (__bf16*)(ws + 64 * MB);
  __bf16* WvT = (__bf16*)(ws + 72 * MB);
  __bf16* WoT = (__bf16*)(ws + 80 * MB);
  __bf16* q_t = (__bf16*)(ws + 112 * MB);
  __bf16* k_t = (__bf16*)(ws + 144 * MB);
  __bf16* v_t = (__bf16*)(ws + 152 * MB);
  __bf16* ob  = (__bf16*)(ws + 160 * MB);

  conv_bf16<<<8192, 256, 0, stream>>>(x, xb, D_ * B_ * S_);
  conv_transpose<<<dim3(128, 128), 256, 0, stream>>>(Wq, WqT, 4096, 4096);
  conv_transpose<<<dim3(32, 128),  256, 0, stream>>>(Wk, WkT, 4096, 1024);
  conv_transpose<<<dim3(32, 128),  256, 0, stream>>>(Wv, WvT, 4096, 1024);
  conv_transpose<<<dim3(128, 128), 256, 0, stream>>>(Wo, WoT, 4096, 4096);

  gemm_bt<1, 32><<<dim3(32, 32), 256, 0, stream>>>(xb, WqT, bq, q_t, 4096, 4096, 4096);
  gemm_bt<1, 8><<<dim3(8, 32),   256, 0, stream>>>(xb, WkT, bk, k_t, 4096, 1024, 4096);
  gemm_bt<2, 8><<<dim3(8, 32),   256, 0, stream>>>(xb, WvT, bv, v_t, 4096, 1024, 4096);

  rope_kernel<<<(NQCH + NKCH) / 256, 256, 0, stream>>>(q_t, k_t, fc, sp);
  flash_attn<<<2048, 256, 0, stream>>>(q_t, k_t, v_t, ob);

  gemm_bt<0, 1><<<dim3(32, 32), 256, 0, stream>>>(ob, WoT, bo, out, 4096, 4096, 4096);
}

// Round 2
// 1015.645 us; speedup vs baseline: 1.2882x; 1.2882x over previous
//
#include <hip/hip_runtime.h>
#include <hip/hip_bf16.h>

using bf16x8   = __attribute__((ext_vector_type(8))) __bf16;
using floatx4  = __attribute__((ext_vector_type(4))) float;
using floatx16 = __attribute__((ext_vector_type(16))) float;

#define DEVINL __device__ __forceinline__

DEVINL void gload16(const void* g, void* l) {
  __builtin_amdgcn_global_load_lds(
      (__attribute__((address_space(1))) void*)g,
      (__attribute__((address_space(3))) void*)l,
      16, 0, 0);
}

constexpr int S_ = 1024, D_ = 4096, HQ_ = 32, HKV_ = 8, HD_ = 128, B_ = 4;

// ---------------- convert x: fp32 -> bf16 ----------------
__global__ void conv_bf16(const float* __restrict__ in, __bf16* __restrict__ out, int n) {
  int i = (blockIdx.x * 256 + threadIdx.x) * 8;
  if (i >= n) return;
  float4 a = *(const float4*)(in + i);
  float4 b = *(const float4*)(in + i + 4);
  bf16x8 o;
  o[0] = (__bf16)a.x; o[1] = (__bf16)a.y; o[2] = (__bf16)a.z; o[3] = (__bf16)a.w;
  o[4] = (__bf16)b.x; o[5] = (__bf16)b.y; o[6] = (__bf16)b.z; o[7] = (__bf16)b.w;
  *(bf16x8*)(out + i) = o;
}

// ---------------- transpose+convert weights: W[K][N] fp32 -> WT[N][K] bf16 ----------------
__global__ void conv_transpose(const float* __restrict__ W, __bf16* __restrict__ WT, int K, int N) {
  __shared__ float tile[32][33];
  int n0 = blockIdx.x * 32, k0 = blockIdx.y * 32;
  int tx = threadIdx.x & 31, ty = threadIdx.x >> 5; // ty 0..7
#pragma unroll
  for (int i = 0; i < 32; i += 8)
    tile[ty + i][tx] = W[(size_t)(k0 + ty + i) * N + n0 + tx];
  __syncthreads();
#pragma unroll
  for (int i = 0; i < 32; i += 8)
    WT[(size_t)(n0 + ty + i) * K + k0 + tx] = (__bf16)tile[tx][ty + i];
}

// ---------------- GEMM: C = A(MxK,bf16) * BT(NxK,bf16)^T + bias ----------------
// MODE 0: plain fp32 out [M][N]
// MODE 1: bf16 out permuted (b,h,s,d):  [b][HH][1024][128]
// MODE 2: bf16 out permuted (b,h,d,s):  [b][HH][128][1024]   (V^T)
template<int MODE, int HH>
__global__ __launch_bounds__(256, 2)
void gemm_bt(const __bf16* __restrict__ A, const __bf16* __restrict__ BT,
             const float* __restrict__ bias, void* __restrict__ Cout,
             int M, int N, int K)
{
  __shared__ __bf16 Alds[4096];
  __shared__ __bf16 Blds[4096];
  const int t = threadIdx.x;
  const int lane = t & 63;
  const int w = t >> 6;
  const int wr = w >> 1, wc = w & 1;
  const int g = lane >> 4, c = lane & 15;
  const int m0 = blockIdx.y * 128, n0 = blockIdx.x * 128;

  const floatx4 zero4 = {0.f, 0.f, 0.f, 0.f};
  floatx4 acc[4][4];
#pragma unroll
  for (int i = 0; i < 4; i++)
#pragma unroll
    for (int j = 0; j < 4; j++) acc[i][j] = zero4;

  const int row = t & 127, kg = t >> 7;
  const __bf16* Ar = A  + (size_t)(m0 + row) * K + kg * 8;
  const __bf16* Br = BT + (size_t)(n0 + row) * K + kg * 8;

  for (int kt = 0; kt < K; kt += 32) {
    gload16(Ar + kt,      &Alds[t * 8]);
    gload16(Ar + kt + 16, &Alds[(t + 256) * 8]);
    gload16(Br + kt,      &Blds[t * 8]);
    gload16(Br + kt + 16, &Blds[(t + 256) * 8]);
    __syncthreads();
    bf16x8 af[4], bf[4];
#pragma unroll
    for (int i = 0; i < 4; i++)
      af[i] = *(const bf16x8*)&Alds[(g * 128 + wr * 64 + i * 16 + c) * 8];
#pragma unroll
    for (int j = 0; j < 4; j++)
      bf[j] = *(const bf16x8*)&Blds[(g * 128 + wc * 64 + j * 16 + c) * 8];
#pragma unroll
    for (int i = 0; i < 4; i++)
#pragma unroll
      for (int j = 0; j < 4; j++)
        acc[i][j] = __builtin_amdgcn_mfma_f32_16x16x32_bf16(af[i], bf[j], acc[i][j], 0, 0, 0);
    __syncthreads();
  }

#pragma unroll
  for (int j = 0; j < 4; j++) {
    const int ncol = n0 + wc * 64 + j * 16 + c;
    const float bv = bias[ncol];
#pragma unroll
    for (int i = 0; i < 4; i++) {
      const int mbase = m0 + wr * 64 + i * 16 + g * 4;
#pragma unroll
      for (int r = 0; r < 4; r++) {
        const int m = mbase + r;
        const float v = acc[i][j][r] + bv;
        if constexpr (MODE == 0) {
          ((float*)Cout)[(size_t)m * N + ncol] = v;
        } else if constexpr (MODE == 1) {
          const int bb = m >> 10, s = m & 1023, hh = ncol >> 7, dd = ncol & 127;
          ((__bf16*)Cout)[(((size_t)bb * HH + hh) * 1024 + s) * 128 + dd] = (__bf16)v;
        } else {
          const int bb = m >> 10, s = m & 1023, hh = ncol >> 7, dd = ncol & 127;
          ((__bf16*)Cout)[(((size_t)bb * HH + hh) * 128 + dd) * 1024 + s] = (__bf16)v;
        }
      }
    }
  }
}

// ---------------- RoPE in-place on q_t (b,h,s,d) and k_t ----------------
constexpr int NQCH = B_ * HQ_ * S_ * (HD_ / 8);
constexpr int NKCH = B_ * HKV_ * S_ * (HD_ / 8);
__global__ void rope_kernel(__bf16* __restrict__ qt, __bf16* __restrict__ kt,
                            const float* __restrict__ fc, const int* __restrict__ sp) {
  int tid = blockIdx.x * 256 + threadIdx.x;
  __bf16* p;
  int idx;
  if (tid < NQCH) { p = qt; idx = tid; }
  else { idx = tid - NQCH; if (idx >= NKCH) return; p = kt; }
  const int c8 = idx & 15;
  const int s  = (idx >> 4) & 1023;
  const int srow = sp[0] + s;
  const float* f = fc + (size_t)srow * 128 + c8 * 8;
  float4 fa = *(const float4*)(f);
  float4 fb = *(const float4*)(f + 4);
  __bf16* q = p + (size_t)idx * 8;
  bf16x8 v = *(const bf16x8*)q;
  float a0 = (float)v[0], b0 = (float)v[1], a1 = (float)v[2], b1 = (float)v[3];
  float a2 = (float)v[4], b2 = (float)v[5], a3 = (float)v[6], b3 = (float)v[7];
  bf16x8 o;
  o[0] = (__bf16)(a0 * fa.x - b0 * fa.y); o[1] = (__bf16)(a0 * fa.y + b0 * fa.x);
  o[2] = (__bf16)(a1 * fa.z - b1 * fa.w); o[3] = (__bf16)(a1 * fa.w + b1 * fa.z);
  o[4] = (__bf16)(a2 * fb.x - b2 * fb.y); o[5] = (__bf16)(a2 * fb.y + b2 * fb.x);
  o[6] = (__bf16)(a3 * fb.z - b3 * fb.w); o[7] = (__bf16)(a3 * fb.w + b3 * fb.z);
  *(bf16x8*)q = o;
}

// ---------------- flash attention: swapped-QK^T 32x32, in-register softmax ----------------
// grid: (b*HQ + h)*8 + qb ; 4 waves; wave w owns q-rows [ (qb + 8w)*32, +32 )
__global__ __launch_bounds__(256, 2)
void flash_attn(const __bf16* __restrict__ qt, const __bf16* __restrict__ kt,
                const __bf16* __restrict__ vt, __bf16* __restrict__ obuf)
{
  const int lane = threadIdx.x & 63, w = threadIdx.x >> 6;
  const int rl = lane & 31, hi = lane >> 5;
  const int qb = blockIdx.x & 7;
  const int bh = blockIdx.x >> 3;
  const int b = bh >> 5, h = bh & 31, hk = h >> 2;
  const int q0w = (qb + w * 8) * 32;

  const __bf16* Qp = qt + (size_t)(b * HQ_ + h) * S_ * HD_;
  const __bf16* Kp = kt + (size_t)(b * HKV_ + hk) * S_ * HD_;
  const __bf16* Vp = vt + (size_t)(b * HKV_ + hk) * HD_ * S_;  // V^T [d][s]

  // Q fragments (B-operand): col=rl -> q row, k=hi*8+j -> head dim
  const __bf16* Qb = Qp + (size_t)(q0w + rl) * HD_ + hi * 8;
  bf16x8 qf[8];
#pragma unroll
  for (int d = 0; d < 8; d++) qf[d] = *(const bf16x8*)(Qb + d * 16);

  const __bf16* Kb = Kp + (size_t)rl * HD_ + hi * 8;
  const __bf16* Vb = Vp + (size_t)rl * S_ + hi * 8;

  const floatx16 zero16 = {0.f,0.f,0.f,0.f,0.f,0.f,0.f,0.f,0.f,0.f,0.f,0.f,0.f,0.f,0.f,0.f};
  floatx16 oacc[4];
#pragma unroll
  for (int dt = 0; dt < 4; dt++) oacc[dt] = zero16;

  float m_run = -__builtin_inff();
  float l_run = 0.f;
  const float ksc = 0.12751744875895f;  // (1/sqrt(128)) * log2(e)

  for (int kv0 = 0; kv0 <= q0w; kv0 += 32) {
    // ---- QK^T (swapped): acc = K_tile * Q_tile -> S^T, lane owns q=rl, k=crow(r,hi)
    floatx16 acc = zero16;
    bf16x8 kf[8];
#pragma unroll
    for (int d = 0; d < 8; d++)
      kf[d] = *(const bf16x8*)(Kb + (size_t)kv0 * HD_ + d * 16);
#pragma unroll
    for (int d = 0; d < 8; d++)
      acc = __builtin_amdgcn_mfma_f32_32x32x16_bf16(kf[d], qf[d], acc, 0, 0, 0);

    // ---- V fragments issued early (latency hides under softmax VALU)
    bf16x8 vf[4][2];
#pragma unroll
    for (int dt = 0; dt < 4; dt++)
#pragma unroll
      for (int kh = 0; kh < 2; kh++)
        vf[dt][kh] = *(const bf16x8*)(Vb + (size_t)dt * 32 * S_ + kv0 + kh * 16);

    // ---- causal mask (diagonal block only; wave-uniform condition)
    if (kv0 == q0w) {
#pragma unroll
      for (int r = 0; r < 16; r++) {
        const int krel = (r & 3) + 8 * (r >> 2) + 4 * hi;
        if (krel > rl) acc[r] = -3e29f;
      }
    }

    // ---- row max (15 in-reg + 1 cross-half shuffle)
    float mx = acc[0];
#pragma unroll
    for (int r = 1; r < 16; r++) mx = fmaxf(mx, acc[r]);
    mx = fmaxf(mx, __shfl_xor(mx, 32));
    const float m_cand = mx * ksc;

    float m_use;
    const bool defer = __all(m_cand - m_run <= 8.0f);
    if (defer) {
      m_use = m_run;           // skip rescale; P bounded by 2^8
    } else {
      const float m_new = fmaxf(m_run, m_cand);
      const float alpha = exp2f(m_run - m_new);   // 0 on first block
      l_run *= alpha;
      // broadcast alpha[q] into the O-accumulator reg layout (q = crow(r,hi))
      float ar[16];
#pragma unroll
      for (int r = 0; r < 16; r++)
        ar[r] = __shfl(alpha, (r & 3) + 8 * (r >> 2) + 4 * hi);
#pragma unroll
      for (int dt = 0; dt < 4; dt++)
#pragma unroll
        for (int r = 0; r < 16; r++) oacc[dt][r] *= ar[r];
      m_run = m_new;
      m_use = m_new;
    }

    // ---- P = exp2(acc*ksc - m) ; row sum
    float pr[16];
#pragma unroll
    for (int r = 0; r < 16; r++) pr[r] = exp2f(fmaf(acc[r], ksc, -m_use));
    float rs = pr[0];
#pragma unroll
    for (int r = 1; r < 16; r++) rs += pr[r];
    rs += __shfl_xor(rs, 32);
    l_run += rs;

    // ---- P (f32, lane-q layout) -> bf16 A-fragments via cvt_pk + permlane32_swap
    bf16x8 pa[2];
#pragma unroll
    for (int kh = 0; kh < 2; kh++) {
      const int rb = kh * 8;
      unsigned a0, b0, a1, b1;
      asm("v_cvt_pk_bf16_f32 %0, %1, %2" : "=v"(a0) : "v"(pr[rb + 0]), "v"(pr[rb + 1]));
      asm("v_cvt_pk_bf16_f32 %0, %1, %2" : "=v"(b0) : "v"(pr[rb + 4]), "v"(pr[rb + 5]));
      asm("v_cvt_pk_bf16_f32 %0, %1, %2" : "=v"(a1) : "v"(pr[rb + 2]), "v"(pr[rb + 3]));
      asm("v_cvt_pk_bf16_f32 %0, %1, %2" : "=v"(b1) : "v"(pr[rb + 6]), "v"(pr[rb + 7]));
      asm("v_permlane32_swap_b32 %0, %1" : "+v"(a0), "+v"(b0));
      asm("v_permlane32_swap_b32 %0, %1" : "+v"(a1), "+v"(b1));
      union { unsigned u[4]; bf16x8 v; } cvt;
      cvt.u[0] = a0; cvt.u[1] = a1; cvt.u[2] = b0; cvt.u[3] = b1;
      pa[kh] = cvt.v;
    }

    // ---- PV: O[q][d] += P * V
#pragma unroll
    for (int dt = 0; dt < 4; dt++) {
      oacc[dt] = __builtin_amdgcn_mfma_f32_32x32x16_bf16(pa[0], vf[dt][0], oacc[dt], 0, 0, 0);
      oacc[dt] = __builtin_amdgcn_mfma_f32_32x32x16_bf16(pa[1], vf[dt][1], oacc[dt], 0, 0, 0);
    }
  }

  // ---- epilogue: O * (1/l), broadcast 1/l into reg layout, store
  const float linv = 1.f / l_run;
  float lr[16];
#pragma unroll
  for (int r = 0; r < 16; r++)
    lr[r] = __shfl(linv, (r & 3) + 8 * (r >> 2) + 4 * hi);
#pragma unroll
  for (int dt = 0; dt < 4; dt++)
#pragma unroll
    for (int r = 0; r < 16; r++) {
      const int qrow = q0w + (r & 3) + 8 * (r >> 2) + 4 * hi;
      const size_t o = (size_t)(b * S_ + qrow) * D_ + h * HD_ + dt * 32 + rl;
      obuf[o] = (__bf16)(oacc[dt][r] * lr[r]);
    }
}

extern "C" void kernel_launch(void* const* d_in, const int* in_sizes, int n_in,
                              void* d_out, int out_size, void* d_ws, size_t ws_size,
                              hipStream_t stream) {
  (void)in_sizes; (void)n_in; (void)out_size;
  const float* x  = (const float*)d_in[0];
  const float* fc = (const float*)d_in[1];
  const float* Wq = (const float*)d_in[2];
  const float* bq = (const float*)d_in[3];
  const float* Wk = (const float*)d_in[4];
  const float* bk = (const float*)d_in[5];
  const float* Wv = (const float*)d_in[6];
  const float* bv = (const float*)d_in[7];
  const float* Wo = (const float*)d_in[8];
  const float* bo = (const float*)d_in[9];
  const int*   sp = (const int*)d_in[10];
  float* out = (float*)d_out;

  const size_t MB = 1024 * 1024;
  if (ws_size < 192 * MB) return;
  char* ws = (char*)d_ws;
  __bf16* xb  = (__bf16*)(ws + 0);
  __bf16* WqT = (__bf16*)(ws + 32 * MB);
  __bf16* WkT = (__bf16*)(ws + 64 * MB);
  __bf16* WvT = (__bf16*)(ws + 72 * MB);
  __bf16* WoT = (__bf16*)(ws + 80 * MB);
  __bf16* q_t = (__bf16*)(ws + 112 * MB);
  __bf16* k_t = (__bf16*)(ws + 144 * MB);
  __bf16* v_t = (__bf16*)(ws + 152 * MB);
  __bf16* ob  = (__bf16*)(ws + 160 * MB);

  conv_bf16<<<8192, 256, 0, stream>>>(x, xb, D_ * B_ * S_);
  conv_transpose<<<dim3(128, 128), 256, 0, stream>>>(Wq, WqT, 4096, 4096);
  conv_transpose<<<dim3(32, 128),  256, 0, stream>>>(Wk, WkT, 4096, 1024);
  conv_transpose<<<dim3(32, 128),  256, 0, stream>>>(Wv, WvT, 4096, 1024);
  conv_transpose<<<dim3(128, 128), 256, 0, stream>>>(Wo, WoT, 4096, 4096);

  gemm_bt<1, 32><<<dim3(32, 32), 256, 0, stream>>>(xb, WqT, bq, q_t, 4096, 4096, 4096);
  gemm_bt<1, 8><<<dim3(8, 32),   256, 0, stream>>>(xb, WkT, bk, k_t, 4096, 1024, 4096);
  gemm_bt<2, 8><<<dim3(8, 32),   256, 0, stream>>>(xb, WvT, bv, v_t, 4096, 1024, 4096);

  rope_kernel<<<(NQCH + NKCH) / 256, 256, 0, stream>>>(q_t, k_t, fc, sp);
  flash_attn<<<1024, 256, 0, stream>>>(q_t, k_t, v_t, ob);

  gemm_bt<0, 1><<<dim3(32, 32), 256, 0, stream>>>(ob, WoT, bo, out, 4096, 4096, 4096);
}

// Round 3
// 696.881 us; speedup vs baseline: 1.8775x; 1.4574x over previous
//
#include <hip/hip_runtime.h>
#include <hip/hip_bf16.h>

using bf16x8   = __attribute__((ext_vector_type(8))) __bf16;
using floatx4  = __attribute__((ext_vector_type(4))) float;
using floatx16 = __attribute__((ext_vector_type(16))) float;

#define DEVINL __device__ __forceinline__

DEVINL void gload16(const void* g, void* l) {
  __builtin_amdgcn_global_load_lds(
      (__attribute__((address_space(1))) void*)g,
      (__attribute__((address_space(3))) void*)l,
      16, 0, 0);
}

constexpr int S_ = 1024, D_ = 4096, HQ_ = 32, HKV_ = 8, HD_ = 128, B_ = 4;

// ---------------- convert x: fp32 -> bf16 ----------------
__global__ void conv_bf16(const float* __restrict__ in, __bf16* __restrict__ out, int n) {
  int i = (blockIdx.x * 256 + threadIdx.x) * 8;
  if (i >= n) return;
  float4 a = *(const float4*)(in + i);
  float4 b = *(const float4*)(in + i + 4);
  bf16x8 o;
  o[0] = (__bf16)a.x; o[1] = (__bf16)a.y; o[2] = (__bf16)a.z; o[3] = (__bf16)a.w;
  o[4] = (__bf16)b.x; o[5] = (__bf16)b.y; o[6] = (__bf16)b.z; o[7] = (__bf16)b.w;
  *(bf16x8*)(out + i) = o;
}

// ---------------- transpose+convert weights: W[K][N] fp32 -> WT[N][K] bf16 ----------------
__global__ void conv_transpose(const float* __restrict__ W, __bf16* __restrict__ WT, int K, int N) {
  __shared__ float tile[32][33];
  int n0 = blockIdx.x * 32, k0 = blockIdx.y * 32;
  int tx = threadIdx.x & 31, ty = threadIdx.x >> 5; // ty 0..7
#pragma unroll
  for (int i = 0; i < 32; i += 8)
    tile[ty + i][tx] = W[(size_t)(k0 + ty + i) * N + n0 + tx];
  __syncthreads();
#pragma unroll
  for (int i = 0; i < 32; i += 8)
    WT[(size_t)(n0 + ty + i) * K + k0 + tx] = (__bf16)tile[tx][ty + i];
}

// ---------------- GEMM: C = A(MxK,bf16) * BT(NxK,bf16)^T + bias ----------------
// LDS tile: row-major [128 rows][4 slots of 16B]; slot s of row r holds k-chunk
// g = s ^ ((r>>1)&3)  (XOR swizzle -> coalesced staging + conflict-free ds_read_b128)
// MODE 0: plain fp32 out [M][N]
// MODE 1: bf16 out permuted (b,h,s,d):  [b][HH][1024][128]
// MODE 2: bf16 out permuted (b,h,d,s):  [b][HH][128][1024]   (V^T)
template<int MODE, int HH>
__global__ __launch_bounds__(256, 2)
void gemm_bt(const __bf16* __restrict__ A, const __bf16* __restrict__ BT,
             const float* __restrict__ bias, void* __restrict__ Cout,
             int M, int N, int K)
{
  __shared__ __bf16 Alds[4096];
  __shared__ __bf16 Blds[4096];
  const int t = threadIdx.x;
  const int lane = t & 63;
  const int w = t >> 6;
  const int wr = w >> 1, wc = w & 1;
  const int g = lane >> 4, c = lane & 15;

  // XCD-aware block swizzle (nwg is a multiple of 8 for all our launches)
  const int nwg = gridDim.x * gridDim.y;
  int lin = blockIdx.y * gridDim.x + blockIdx.x;
  lin = (lin & 7) * (nwg >> 3) + (lin >> 3);
  const int bx = lin % gridDim.x, by = lin / gridDim.x;
  const int m0 = by * 128, n0 = bx * 128;

  const floatx4 zero4 = {0.f, 0.f, 0.f, 0.f};
  floatx4 acc[4][4];
#pragma unroll
  for (int i = 0; i < 4; i++)
#pragma unroll
    for (int j = 0; j < 4; j++) acc[i][j] = zero4;

  // staging: thread t stages rows (t>>2) and (t>>2)+64, pre-swizzled k-chunk ga
  const int srow = t >> 2;
  const int ga = (t & 3) ^ ((t >> 3) & 3);
  const __bf16* Ar = A  + (size_t)(m0 + srow) * K + ga * 8;
  const __bf16* Br = BT + (size_t)(n0 + srow) * K + ga * 8;
  const size_t rstep = (size_t)64 * K;

  // fragment read offsets (elements): row*32 + swizzled_slot*8
  const int sl = (g ^ ((c >> 1) & 3)) * 8;
  const int aoff = (wr * 64 + c) * 32 + sl;
  const int boff = (wc * 64 + c) * 32 + sl;

  for (int kt = 0; kt < K; kt += 32) {
    gload16(Ar + kt,         &Alds[t * 8]);
    gload16(Ar + rstep + kt, &Alds[(t + 256) * 8]);
    gload16(Br + kt,         &Blds[t * 8]);
    gload16(Br + rstep + kt, &Blds[(t + 256) * 8]);
    __syncthreads();
    bf16x8 af[4], bf[4];
#pragma unroll
    for (int i = 0; i < 4; i++)
      af[i] = *(const bf16x8*)&Alds[aoff + i * 512];
#pragma unroll
    for (int j = 0; j < 4; j++)
      bf[j] = *(const bf16x8*)&Blds[boff + j * 512];
#pragma unroll
    for (int i = 0; i < 4; i++)
#pragma unroll
      for (int j = 0; j < 4; j++)
        acc[i][j] = __builtin_amdgcn_mfma_f32_16x16x32_bf16(af[i], bf[j], acc[i][j], 0, 0, 0);
    __syncthreads();
  }

#pragma unroll
  for (int j = 0; j < 4; j++) {
    const int ncol = n0 + wc * 64 + j * 16 + c;
    const float bv = bias[ncol];
#pragma unroll
    for (int i = 0; i < 4; i++) {
      const int mbase = m0 + wr * 64 + i * 16 + g * 4;
#pragma unroll
      for (int r = 0; r < 4; r++) {
        const int m = mbase + r;
        const float v = acc[i][j][r] + bv;
        if constexpr (MODE == 0) {
          ((float*)Cout)[(size_t)m * N + ncol] = v;
        } else if constexpr (MODE == 1) {
          const int bb = m >> 10, s = m & 1023, hh = ncol >> 7, dd = ncol & 127;
          ((__bf16*)Cout)[(((size_t)bb * HH + hh) * 1024 + s) * 128 + dd] = (__bf16)v;
        } else {
          const int bb = m >> 10, s = m & 1023, hh = ncol >> 7, dd = ncol & 127;
          ((__bf16*)Cout)[(((size_t)bb * HH + hh) * 128 + dd) * 1024 + s] = (__bf16)v;
        }
      }
    }
  }
}

// ---------------- RoPE in-place on q_t (b,h,s,d) and k_t ----------------
constexpr int NQCH = B_ * HQ_ * S_ * (HD_ / 8);
constexpr int NKCH = B_ * HKV_ * S_ * (HD_ / 8);
__global__ void rope_kernel(__bf16* __restrict__ qt, __bf16* __restrict__ kt,
                            const float* __restrict__ fc, const int* __restrict__ sp) {
  int tid = blockIdx.x * 256 + threadIdx.x;
  __bf16* p;
  int idx;
  if (tid < NQCH) { p = qt; idx = tid; }
  else { idx = tid - NQCH; if (idx >= NKCH) return; p = kt; }
  const int c8 = idx & 15;
  const int s  = (idx >> 4) & 1023;
  const int srow = sp[0] + s;
  const float* f = fc + (size_t)srow * 128 + c8 * 8;
  float4 fa = *(const float4*)(f);
  float4 fb = *(const float4*)(f + 4);
  __bf16* q = p + (size_t)idx * 8;
  bf16x8 v = *(const bf16x8*)q;
  float a0 = (float)v[0], b0 = (float)v[1], a1 = (float)v[2], b1 = (float)v[3];
  float a2 = (float)v[4], b2 = (float)v[5], a3 = (float)v[6], b3 = (float)v[7];
  bf16x8 o;
  o[0] = (__bf16)(a0 * fa.x - b0 * fa.y); o[1] = (__bf16)(a0 * fa.y + b0 * fa.x);
  o[2] = (__bf16)(a1 * fa.z - b1 * fa.w); o[3] = (__bf16)(a1 * fa.w + b1 * fa.z);
  o[4] = (__bf16)(a2 * fb.x - b2 * fb.y); o[5] = (__bf16)(a2 * fb.y + b2 * fb.x);
  o[6] = (__bf16)(a3 * fb.z - b3 * fb.w); o[7] = (__bf16)(a3 * fb.w + b3 * fb.z);
  *(bf16x8*)q = o;
}

// ---------------- flash attention: swapped-QK^T 32x32, in-register softmax ----------------
// grid: (b*HQ + h)*8 + qb ; 4 waves; wave w owns q-rows [ (qb + 8w)*32, +32 )
__global__ __launch_bounds__(256, 2)
void flash_attn(const __bf16* __restrict__ qt, const __bf16* __restrict__ kt,
                const __bf16* __restrict__ vt, __bf16* __restrict__ obuf)
{
  const int lane = threadIdx.x & 63, w = threadIdx.x >> 6;
  const int rl = lane & 31, hi = lane >> 5;
  const int qb = blockIdx.x & 7;
  const int bh = blockIdx.x >> 3;
  const int b = bh >> 5, h = bh & 31, hk = h >> 2;
  const int q0w = (qb + w * 8) * 32;

  const __bf16* Qp = qt + (size_t)(b * HQ_ + h) * S_ * HD_;
  const __bf16* Kp = kt + (size_t)(b * HKV_ + hk) * S_ * HD_;
  const __bf16* Vp = vt + (size_t)(b * HKV_ + hk) * HD_ * S_;  // V^T [d][s]

  const __bf16* Qb = Qp + (size_t)(q0w + rl) * HD_ + hi * 8;
  bf16x8 qf[8];
#pragma unroll
  for (int d = 0; d < 8; d++) qf[d] = *(const bf16x8*)(Qb + d * 16);

  const __bf16* Kb = Kp + (size_t)rl * HD_ + hi * 8;
  const __bf16* Vb = Vp + (size_t)rl * S_ + hi * 8;

  const floatx16 zero16 = {0.f,0.f,0.f,0.f,0.f,0.f,0.f,0.f,0.f,0.f,0.f,0.f,0.f,0.f,0.f,0.f};
  floatx16 oacc[4];
#pragma unroll
  for (int dt = 0; dt < 4; dt++) oacc[dt] = zero16;

  float m_run = -__builtin_inff();
  float l_run = 0.f;
  const float ksc = 0.12751744875895f;  // (1/sqrt(128)) * log2(e)

  for (int kv0 = 0; kv0 <= q0w; kv0 += 32) {
    floatx16 acc = zero16;
    bf16x8 kf[8];
#pragma unroll
    for (int d = 0; d < 8; d++)
      kf[d] = *(const bf16x8*)(Kb + (size_t)kv0 * HD_ + d * 16);
#pragma unroll
    for (int d = 0; d < 8; d++)
      acc = __builtin_amdgcn_mfma_f32_32x32x16_bf16(kf[d], qf[d], acc, 0, 0, 0);

    bf16x8 vf[4][2];
#pragma unroll
    for (int dt = 0; dt < 4; dt++)
#pragma unroll
      for (int kh = 0; kh < 2; kh++)
        vf[dt][kh] = *(const bf16x8*)(Vb + (size_t)dt * 32 * S_ + kv0 + kh * 16);

    if (kv0 == q0w) {
#pragma unroll
      for (int r = 0; r < 16; r++) {
        const int krel = (r & 3) + 8 * (r >> 2) + 4 * hi;
        if (krel > rl) acc[r] = -3e29f;
      }
    }

    float mx = acc[0];
#pragma unroll
    for (int r = 1; r < 16; r++) mx = fmaxf(mx, acc[r]);
    mx = fmaxf(mx, __shfl_xor(mx, 32));
    const float m_cand = mx * ksc;

    float m_use;
    const bool defer = __all(m_cand - m_run <= 8.0f);
    if (defer) {
      m_use = m_run;
    } else {
      const float m_new = fmaxf(m_run, m_cand);
      const float alpha = exp2f(m_run - m_new);
      l_run *= alpha;
      float ar[16];
#pragma unroll
      for (int r = 0; r < 16; r++)
        ar[r] = __shfl(alpha, (r & 3) + 8 * (r >> 2) + 4 * hi);
#pragma unroll
      for (int dt = 0; dt < 4; dt++)
#pragma unroll
        for (int r = 0; r < 16; r++) oacc[dt][r] *= ar[r];
      m_run = m_new;
      m_use = m_new;
    }

    float pr[16];
#pragma unroll
    for (int r = 0; r < 16; r++) pr[r] = exp2f(fmaf(acc[r], ksc, -m_use));
    float rs = pr[0];
#pragma unroll
    for (int r = 1; r < 16; r++) rs += pr[r];
    rs += __shfl_xor(rs, 32);
    l_run += rs;

    bf16x8 pa[2];
#pragma unroll
    for (int kh = 0; kh < 2; kh++) {
      const int rb = kh * 8;
      unsigned a0, b0, a1, b1;
      asm("v_cvt_pk_bf16_f32 %0, %1, %2" : "=v"(a0) : "v"(pr[rb + 0]), "v"(pr[rb + 1]));
      asm("v_cvt_pk_bf16_f32 %0, %1, %2" : "=v"(b0) : "v"(pr[rb + 4]), "v"(pr[rb + 5]));
      asm("v_cvt_pk_bf16_f32 %0, %1, %2" : "=v"(a1) : "v"(pr[rb + 2]), "v"(pr[rb + 3]));
      asm("v_cvt_pk_bf16_f32 %0, %1, %2" : "=v"(b1) : "v"(pr[rb + 6]), "v"(pr[rb + 7]));
      asm("v_permlane32_swap_b32 %0, %1" : "+v"(a0), "+v"(b0));
      asm("v_permlane32_swap_b32 %0, %1" : "+v"(a1), "+v"(b1));
      union { unsigned u[4]; bf16x8 v; } cvt;
      cvt.u[0] = a0; cvt.u[1] = a1; cvt.u[2] = b0; cvt.u[3] = b1;
      pa[kh] = cvt.v;
    }

#pragma unroll
    for (int dt = 0; dt < 4; dt++) {
      oacc[dt] = __builtin_amdgcn_mfma_f32_32x32x16_bf16(pa[0], vf[dt][0], oacc[dt], 0, 0, 0);
      oacc[dt] = __builtin_amdgcn_mfma_f32_32x32x16_bf16(pa[1], vf[dt][1], oacc[dt], 0, 0, 0);
    }
  }

  const float linv = 1.f / l_run;
  float lr[16];
#pragma unroll
  for (int r = 0; r < 16; r++)
    lr[r] = __shfl(linv, (r & 3) + 8 * (r >> 2) + 4 * hi);
#pragma unroll
  for (int dt = 0; dt < 4; dt++)
#pragma unroll
    for (int r = 0; r < 16; r++) {
      const int qrow = q0w + (r & 3) + 8 * (r >> 2) + 4 * hi;
      const size_t o = (size_t)(b * S_ + qrow) * D_ + h * HD_ + dt * 32 + rl;
      obuf[o] = (__bf16)(oacc[dt][r] * lr[r]);
    }
}

extern "C" void kernel_launch(void* const* d_in, const int* in_sizes, int n_in,
                              void* d_out, int out_size, void* d_ws, size_t ws_size,
                              hipStream_t stream) {
  (void)in_sizes; (void)n_in; (void)out_size;
  const float* x  = (const float*)d_in[0];
  const float* fc = (const float*)d_in[1];
  const float* Wq = (const float*)d_in[2];
  const float* bq = (const float*)d_in[3];
  const float* Wk = (const float*)d_in[4];
  const float* bk = (const float*)d_in[5];
  const float* Wv = (const float*)d_in[6];
  const float* bv = (const float*)d_in[7];
  const float* Wo = (const float*)d_in[8];
  const float* bo = (const float*)d_in[9];
  const int*   sp = (const int*)d_in[10];
  float* out = (float*)d_out;

  const size_t MB = 1024 * 1024;
  if (ws_size < 192 * MB) return;
  char* ws = (char*)d_ws;
  __bf16* xb  = (__bf16*)(ws + 0);
  __bf16* WqT = (__bf16*)(ws + 32 * MB);
  __bf16* WkT = (__bf16*)(ws + 64 * MB);
  __bf16* WvT = (__bf16*)(ws + 72 * MB);
  __bf16* WoT = (__bf16*)(ws + 80 * MB);
  __bf16* q_t = (__bf16*)(ws + 112 * MB);
  __bf16* k_t = (__bf16*)(ws + 144 * MB);
  __bf16* v_t = (__bf16*)(ws + 152 * MB);
  __bf16* ob  = (__bf16*)(ws + 160 * MB);

  conv_bf16<<<8192, 256, 0, stream>>>(x, xb, D_ * B_ * S_);
  conv_transpose<<<dim3(128, 128), 256, 0, stream>>>(Wq, WqT, 4096, 4096);
  conv_transpose<<<dim3(32, 128),  256, 0, stream>>>(Wk, WkT, 4096, 1024);
  conv_transpose<<<dim3(32, 128),  256, 0, stream>>>(Wv, WvT, 4096, 1024);
  conv_transpose<<<dim3(128, 128), 256, 0, stream>>>(Wo, WoT, 4096, 4096);

  gemm_bt<1, 32><<<dim3(32, 32), 256, 0, stream>>>(xb, WqT, bq, q_t, 4096, 4096, 4096);
  gemm_bt<1, 8><<<dim3(8, 32),   256, 0, stream>>>(xb, WkT, bk, k_t, 4096, 1024, 4096);
  gemm_bt<2, 8><<<dim3(8, 32),   256, 0, stream>>>(xb, WvT, bv, v_t, 4096, 1024, 4096);

  rope_kernel<<<(NQCH + NKCH) / 256, 256, 0, stream>>>(q_t, k_t, fc, sp);
  flash_attn<<<1024, 256, 0, stream>>>(q_t, k_t, v_t, ob);

  gemm_bt<0, 1><<<dim3(32, 32), 256, 0, stream>>>(ob, WoT, bo, out, 4096, 4096, 4096);
}

// Round 4
// 664.300 us; speedup vs baseline: 1.9695x; 1.0490x over previous
//
#include <hip/hip_runtime.h>
#include <hip/hip_bf16.h>

using bf16x8   = __attribute__((ext_vector_type(8))) __bf16;
using floatx4  = __attribute__((ext_vector_type(4))) float;
using floatx16 = __attribute__((ext_vector_type(16))) float;

#define DEVINL __device__ __forceinline__

DEVINL void gload16(const void* g, void* l) {
  __builtin_amdgcn_global_load_lds(
      (__attribute__((address_space(1))) void*)g,
      (__attribute__((address_space(3))) void*)l,
      16, 0, 0);
}

constexpr int S_ = 1024, D_ = 4096, HQ_ = 32, HKV_ = 8, HD_ = 128, B_ = 4;

// ---------------- convert x: fp32 -> bf16 ----------------
__global__ void conv_bf16(const float* __restrict__ in, __bf16* __restrict__ out, int n) {
  int i = (blockIdx.x * 256 + threadIdx.x) * 8;
  if (i >= n) return;
  float4 a = *(const float4*)(in + i);
  float4 b = *(const float4*)(in + i + 4);
  bf16x8 o;
  o[0] = (__bf16)a.x; o[1] = (__bf16)a.y; o[2] = (__bf16)a.z; o[3] = (__bf16)a.w;
  o[4] = (__bf16)b.x; o[5] = (__bf16)b.y; o[6] = (__bf16)b.z; o[7] = (__bf16)b.w;
  *(bf16x8*)(out + i) = o;
}

// ---------------- transpose+convert weights: W[K][N] fp32 -> WT[N][K] bf16 ----------------
__global__ void conv_transpose(const float* __restrict__ W, __bf16* __restrict__ WT, int K, int N) {
  __shared__ float tile[32][33];
  int n0 = blockIdx.x * 32, k0 = blockIdx.y * 32;
  int tx = threadIdx.x & 31, ty = threadIdx.x >> 5; // ty 0..7
#pragma unroll
  for (int i = 0; i < 32; i += 8)
    tile[ty + i][tx] = W[(size_t)(k0 + ty + i) * N + n0 + tx];
  __syncthreads();
#pragma unroll
  for (int i = 0; i < 32; i += 8)
    WT[(size_t)(n0 + ty + i) * K + k0 + tx] = (__bf16)tile[tx][ty + i];
}

// ---------------- deep-pipelined GEMM: C = A(MxK) * BT(NxK)^T + bias ----------------
// 128(M) x 256(N) tile, BK=32, 512 threads = 8 waves (2M x 4N), 4 LDS K-tile buffers,
// prefetch distance 2 K-tiles, counted vmcnt(3), setprio around MFMA cluster.
// LDS per buffer: A 128x32 (8KB) + B 256x32 (16KB) = 24KB; 4 buffers = 96KB.
// Chunk-XOR swizzle: phys_chunk = logical_chunk ^ ((row>>1)&3)  (2-way = free on ds_read_b128).
// MODE 0: fp32 out [M][N], bias b0.
// MODE 1: fused QKV epilogue: cols [0,4096) -> q (b,h,s,d); [4096,5120) -> k (b,h,s,d);
//         [5120,6144) -> v^T (b,h,d,s).  Cout = q base; k at +16777216, v at +20971520 elems.
template<int MODE>
__global__ __launch_bounds__(512, 2)
void gemm8(const __bf16* __restrict__ A, const __bf16* __restrict__ BT,
           const float* __restrict__ b0, const float* __restrict__ b1,
           const float* __restrict__ b2, void* __restrict__ Cout,
           int M, int N, int K)
{
  __shared__ __bf16 lds[49152];  // 4 x (4096 A + 8192 B) elems
  const int t = threadIdx.x;
  const int lane = t & 63, w = t >> 6;
  const int wm = w >> 2, wn = w & 3;
  const int g = lane >> 4, c = lane & 15;

  // XCD-aware bijective swizzle (nwg % 8 == 0 for all our launches)
  const int gridX = gridDim.x;
  const int nwg = gridDim.x * gridDim.y;
  int lin = blockIdx.y * gridDim.x + blockIdx.x;
  lin = (lin & 7) * (nwg >> 3) + (lin >> 3);
  const int bx = lin % gridX, by = lin / gridX;
  const int m0 = by * 128, n0 = bx * 256;

  const floatx4 zero4 = {0.f, 0.f, 0.f, 0.f};
  floatx4 acc[4][4];
#pragma unroll
  for (int i = 0; i < 4; i++)
#pragma unroll
    for (int j = 0; j < 4; j++) acc[i][j] = zero4;

  // staging addresses: thread t stages A row t>>2, B rows t>>2 and t>>2+128,
  // physical chunk t&3 holds logical chunk (t&3)^((t>>3)&3)
  const int arow = t >> 2;
  const int achk = (t & 3) ^ ((t >> 3) & 3);
  const __bf16* Ag  = A  + (size_t)(m0 + arow) * K + achk * 8;
  const __bf16* Bg0 = BT + (size_t)(n0 + arow) * K + achk * 8;
  const __bf16* Bg1 = BT + (size_t)(n0 + arow + 128) * K + achk * 8;

  // fragment read offsets: row*32 + swizzled_chunk*8
  const int sl = (g ^ ((c >> 1) & 3)) * 8;
  const int abase = (wm * 64 + c) * 32 + sl;          // + i*512
  const int bbase = 4096 + (wn * 64 + c) * 32 + sl;   // + j*512

  const int NT = K >> 5;

  auto STAGE = [&](int kt) {
    const int buf = (kt & 3) * 12288;
    const size_t ko = (size_t)kt * 32;
    gload16(Ag  + ko, &lds[buf + t * 8]);
    gload16(Bg0 + ko, &lds[buf + 4096 + t * 8]);
    gload16(Bg1 + ko, &lds[buf + 8192 + t * 8]);
  };

  // prologue: tiles 0 and 1 in flight; wait tile 0 (3 of 6 outstanding)
  STAGE(0);
  STAGE(1);
  asm volatile("s_waitcnt vmcnt(3)" ::: "memory");
  __builtin_amdgcn_s_barrier();
  __builtin_amdgcn_sched_barrier(0);

  for (int kt = 0; kt < NT; ++kt) {
    const int buf = (kt & 3) * 12288;
    // ds_read this tile's fragments
    bf16x8 af[4], bfr[4];
#pragma unroll
    for (int i = 0; i < 4; i++)
      af[i] = *(const bf16x8*)&lds[buf + abase + i * 512];
#pragma unroll
    for (int j = 0; j < 4; j++)
      bfr[j] = *(const bf16x8*)&lds[buf + bbase + j * 512];
    // prefetch tile kt+2
    if (kt + 2 < NT) STAGE(kt + 2);
    __builtin_amdgcn_sched_barrier(0);
    __builtin_amdgcn_s_barrier();
    __builtin_amdgcn_sched_barrier(0);
    __builtin_amdgcn_s_setprio(1);
#pragma unroll
    for (int i = 0; i < 4; i++)
#pragma unroll
      for (int j = 0; j < 4; j++)
        acc[i][j] = __builtin_amdgcn_mfma_f32_16x16x32_bf16(af[i], bfr[j], acc[i][j], 0, 0, 0);
    __builtin_amdgcn_s_setprio(0);
    __builtin_amdgcn_sched_barrier(0);
    if (kt + 2 < NT) { asm volatile("s_waitcnt vmcnt(3)" ::: "memory"); }
    else             { asm volatile("s_waitcnt vmcnt(0)" ::: "memory"); }
    __builtin_amdgcn_s_barrier();
    __builtin_amdgcn_sched_barrier(0);
  }

  // epilogue
#pragma unroll
  for (int j = 0; j < 4; j++) {
    const int ncol = n0 + wn * 64 + j * 16 + c;
#pragma unroll
    for (int i = 0; i < 4; i++) {
      const int mbase = m0 + wm * 64 + i * 16 + g * 4;
#pragma unroll
      for (int r = 0; r < 4; r++) {
        const int m = mbase + r;
        float v = acc[i][j][r];
        if constexpr (MODE == 0) {
          ((float*)Cout)[(size_t)m * N + ncol] = v + b0[ncol];
        } else {
          const int bb = m >> 10, s = m & 1023;
          __bf16* qkv = (__bf16*)Cout;
          if (ncol < 4096) {
            v += b0[ncol];
            const int h = ncol >> 7, d = ncol & 127;
            qkv[(((size_t)bb * 32 + h) * 1024 + s) * 128 + d] = (__bf16)v;
          } else if (ncol < 5120) {
            const int nc = ncol - 4096;
            v += b1[nc];
            const int h = nc >> 7, d = nc & 127;
            qkv[16777216 + (((size_t)bb * 8 + h) * 1024 + s) * 128 + d] = (__bf16)v;
          } else {
            const int nc = ncol - 5120;
            v += b2[nc];
            const int h = nc >> 7, d = nc & 127;
            qkv[20971520 + (((size_t)bb * 8 + h) * 128 + d) * 1024 + s] = (__bf16)v;
          }
        }
      }
    }
  }
}

// ---------------- RoPE in-place on q_t (b,h,s,d) and k_t ----------------
constexpr int NQCH = B_ * HQ_ * S_ * (HD_ / 8);
constexpr int NKCH = B_ * HKV_ * S_ * (HD_ / 8);
__global__ void rope_kernel(__bf16* __restrict__ qt, __bf16* __restrict__ kt,
                            const float* __restrict__ fc, const int* __restrict__ sp) {
  int tid = blockIdx.x * 256 + threadIdx.x;
  __bf16* p;
  int idx;
  if (tid < NQCH) { p = qt; idx = tid; }
  else { idx = tid - NQCH; if (idx >= NKCH) return; p = kt; }
  const int c8 = idx & 15;
  const int s  = (idx >> 4) & 1023;
  const int srow = sp[0] + s;
  const float* f = fc + (size_t)srow * 128 + c8 * 8;
  float4 fa = *(const float4*)(f);
  float4 fb = *(const float4*)(f + 4);
  __bf16* q = p + (size_t)idx * 8;
  bf16x8 v = *(const bf16x8*)q;
  float a0 = (float)v[0], b0 = (float)v[1], a1 = (float)v[2], b1 = (float)v[3];
  float a2 = (float)v[4], b2 = (float)v[5], a3 = (float)v[6], b3 = (float)v[7];
  bf16x8 o;
  o[0] = (__bf16)(a0 * fa.x - b0 * fa.y); o[1] = (__bf16)(a0 * fa.y + b0 * fa.x);
  o[2] = (__bf16)(a1 * fa.z - b1 * fa.w); o[3] = (__bf16)(a1 * fa.w + b1 * fa.z);
  o[4] = (__bf16)(a2 * fb.x - b2 * fb.y); o[5] = (__bf16)(a2 * fb.y + b2 * fb.x);
  o[6] = (__bf16)(a3 * fb.z - b3 * fb.w); o[7] = (__bf16)(a3 * fb.w + b3 * fb.z);
  *(bf16x8*)q = o;
}

// ---------------- flash attention: swapped-QK^T 32x32, in-register softmax ----------------
__global__ __launch_bounds__(256, 2)
void flash_attn(const __bf16* __restrict__ qt, const __bf16* __restrict__ kt,
                const __bf16* __restrict__ vt, __bf16* __restrict__ obuf)
{
  const int lane = threadIdx.x & 63, w = threadIdx.x >> 6;
  const int rl = lane & 31, hi = lane >> 5;
  const int qb = blockIdx.x & 7;
  const int bh = blockIdx.x >> 3;
  const int b = bh >> 5, h = bh & 31, hk = h >> 2;
  const int q0w = (qb + w * 8) * 32;

  const __bf16* Qp = qt + (size_t)(b * HQ_ + h) * S_ * HD_;
  const __bf16* Kp = kt + (size_t)(b * HKV_ + hk) * S_ * HD_;
  const __bf16* Vp = vt + (size_t)(b * HKV_ + hk) * HD_ * S_;  // V^T [d][s]

  const __bf16* Qb = Qp + (size_t)(q0w + rl) * HD_ + hi * 8;
  bf16x8 qf[8];
#pragma unroll
  for (int d = 0; d < 8; d++) qf[d] = *(const bf16x8*)(Qb + d * 16);

  const __bf16* Kb = Kp + (size_t)rl * HD_ + hi * 8;
  const __bf16* Vb = Vp + (size_t)rl * S_ + hi * 8;

  const floatx16 zero16 = {0.f,0.f,0.f,0.f,0.f,0.f,0.f,0.f,0.f,0.f,0.f,0.f,0.f,0.f,0.f,0.f};
  floatx16 oacc[4];
#pragma unroll
  for (int dt = 0; dt < 4; dt++) oacc[dt] = zero16;

  float m_run = -__builtin_inff();
  float l_run = 0.f;
  const float ksc = 0.12751744875895f;  // (1/sqrt(128)) * log2(e)

  for (int kv0 = 0; kv0 <= q0w; kv0 += 32) {
    floatx16 acc = zero16;
    bf16x8 kf[8];
#pragma unroll
    for (int d = 0; d < 8; d++)
      kf[d] = *(const bf16x8*)(Kb + (size_t)kv0 * HD_ + d * 16);
#pragma unroll
    for (int d = 0; d < 8; d++)
      acc = __builtin_amdgcn_mfma_f32_32x32x16_bf16(kf[d], qf[d], acc, 0, 0, 0);

    bf16x8 vf[4][2];
#pragma unroll
    for (int dt = 0; dt < 4; dt++)
#pragma unroll
      for (int kh = 0; kh < 2; kh++)
        vf[dt][kh] = *(const bf16x8*)(Vb + (size_t)dt * 32 * S_ + kv0 + kh * 16);

    if (kv0 == q0w) {
#pragma unroll
      for (int r = 0; r < 16; r++) {
        const int krel = (r & 3) + 8 * (r >> 2) + 4 * hi;
        if (krel > rl) acc[r] = -3e29f;
      }
    }

    float mx = acc[0];
#pragma unroll
    for (int r = 1; r < 16; r++) mx = fmaxf(mx, acc[r]);
    mx = fmaxf(mx, __shfl_xor(mx, 32));
    const float m_cand = mx * ksc;

    float m_use;
    const bool defer = __all(m_cand - m_run <= 8.0f);
    if (defer) {
      m_use = m_run;
    } else {
      const float m_new = fmaxf(m_run, m_cand);
      const float alpha = exp2f(m_run - m_new);
      l_run *= alpha;
      float ar[16];
#pragma unroll
      for (int r = 0; r < 16; r++)
        ar[r] = __shfl(alpha, (r & 3) + 8 * (r >> 2) + 4 * hi);
#pragma unroll
      for (int dt = 0; dt < 4; dt++)
#pragma unroll
        for (int r = 0; r < 16; r++) oacc[dt][r] *= ar[r];
      m_run = m_new;
      m_use = m_new;
    }

    float pr[16];
#pragma unroll
    for (int r = 0; r < 16; r++) pr[r] = exp2f(fmaf(acc[r], ksc, -m_use));
    float rs = pr[0];
#pragma unroll
    for (int r = 1; r < 16; r++) rs += pr[r];
    rs += __shfl_xor(rs, 32);
    l_run += rs;

    bf16x8 pa[2];
#pragma unroll
    for (int kh = 0; kh < 2; kh++) {
      const int rb = kh * 8;
      unsigned a0, b0, a1, b1;
      asm("v_cvt_pk_bf16_f32 %0, %1, %2" : "=v"(a0) : "v"(pr[rb + 0]), "v"(pr[rb + 1]));
      asm("v_cvt_pk_bf16_f32 %0, %1, %2" : "=v"(b0) : "v"(pr[rb + 4]), "v"(pr[rb + 5]));
      asm("v_cvt_pk_bf16_f32 %0, %1, %2" : "=v"(a1) : "v"(pr[rb + 2]), "v"(pr[rb + 3]));
      asm("v_cvt_pk_bf16_f32 %0, %1, %2" : "=v"(b1) : "v"(pr[rb + 6]), "v"(pr[rb + 7]));
      asm("v_permlane32_swap_b32 %0, %1" : "+v"(a0), "+v"(b0));
      asm("v_permlane32_swap_b32 %0, %1" : "+v"(a1), "+v"(b1));
      union { unsigned u[4]; bf16x8 v; } cvt;
      cvt.u[0] = a0; cvt.u[1] = a1; cvt.u[2] = b0; cvt.u[3] = b1;
      pa[kh] = cvt.v;
    }

#pragma unroll
    for (int dt = 0; dt < 4; dt++) {
      oacc[dt] = __builtin_amdgcn_mfma_f32_32x32x16_bf16(pa[0], vf[dt][0], oacc[dt], 0, 0, 0);
      oacc[dt] = __builtin_amdgcn_mfma_f32_32x32x16_bf16(pa[1], vf[dt][1], oacc[dt], 0, 0, 0);
    }
  }

  const float linv = 1.f / l_run;
  float lr[16];
#pragma unroll
  for (int r = 0; r < 16; r++)
    lr[r] = __shfl(linv, (r & 3) + 8 * (r >> 2) + 4 * hi);
#pragma unroll
  for (int dt = 0; dt < 4; dt++)
#pragma unroll
    for (int r = 0; r < 16; r++) {
      const int qrow = q0w + (r & 3) + 8 * (r >> 2) + 4 * hi;
      const size_t o = (size_t)(b * S_ + qrow) * D_ + h * HD_ + dt * 32 + rl;
      obuf[o] = (__bf16)(oacc[dt][r] * lr[r]);
    }
}

extern "C" void kernel_launch(void* const* d_in, const int* in_sizes, int n_in,
                              void* d_out, int out_size, void* d_ws, size_t ws_size,
                              hipStream_t stream) {
  (void)in_sizes; (void)n_in; (void)out_size;
  const float* x  = (const float*)d_in[0];
  const float* fc = (const float*)d_in[1];
  const float* Wq = (const float*)d_in[2];
  const float* bq = (const float*)d_in[3];
  const float* Wk = (const float*)d_in[4];
  const float* bk = (const float*)d_in[5];
  const float* Wv = (const float*)d_in[6];
  const float* bv = (const float*)d_in[7];
  const float* Wo = (const float*)d_in[8];
  const float* bo = (const float*)d_in[9];
  const int*   sp = (const int*)d_in[10];
  float* out = (float*)d_out;

  const size_t MB = 1024 * 1024;
  if (ws_size < 192 * MB) return;
  char* ws = (char*)d_ws;
  __bf16* xb     = (__bf16*)(ws + 0);        // 32 MB
  __bf16* WqkvT  = (__bf16*)(ws + 32 * MB);  // 48 MB: Wq^T | Wk^T | Wv^T  [6144][4096]
  __bf16* WoT    = (__bf16*)(ws + 80 * MB);  // 32 MB
  __bf16* q_t    = (__bf16*)(ws + 112 * MB); // 32 MB (b,h,s,d)
  __bf16* k_t    = (__bf16*)(ws + 144 * MB); //  8 MB (b,h,s,d)
  __bf16* v_t    = (__bf16*)(ws + 152 * MB); //  8 MB (b,h,d,s)
  __bf16* ob     = (__bf16*)(ws + 160 * MB); // 32 MB

  conv_bf16<<<8192, 256, 0, stream>>>(x, xb, D_ * B_ * S_);
  conv_transpose<<<dim3(128, 128), 256, 0, stream>>>(Wq, WqkvT, 4096, 4096);
  conv_transpose<<<dim3(32, 128),  256, 0, stream>>>(Wk, WqkvT + (size_t)4096 * 4096, 4096, 1024);
  conv_transpose<<<dim3(32, 128),  256, 0, stream>>>(Wv, WqkvT + (size_t)5120 * 4096, 4096, 1024);
  conv_transpose<<<dim3(128, 128), 256, 0, stream>>>(Wo, WoT, 4096, 4096);

  // fused QKV projection: [4096 x 6144] = xb @ [Wq|Wk|Wv]
  gemm8<1><<<dim3(24, 32), 512, 0, stream>>>(xb, WqkvT, bq, bk, bv, q_t, 4096, 6144, 4096);

  rope_kernel<<<(NQCH + NKCH) / 256, 256, 0, stream>>>(q_t, k_t, fc, sp);
  flash_attn<<<1024, 256, 0, stream>>>(q_t, k_t, v_t, ob);

  gemm8<0><<<dim3(16, 32), 512, 0, stream>>>(ob, WoT, bo, nullptr, nullptr, out, 4096, 4096, 4096);
}

// Round 5
// 617.820 us; speedup vs baseline: 2.1177x; 1.0752x over previous
//
#include <hip/hip_runtime.h>
#include <hip/hip_bf16.h>

using bf16x8   = __attribute__((ext_vector_type(8))) __bf16;
using floatx4  = __attribute__((ext_vector_type(4))) float;
using floatx16 = __attribute__((ext_vector_type(16))) float;

#define DEVINL __device__ __forceinline__

DEVINL void gload16(const void* g, void* l) {
  __builtin_amdgcn_global_load_lds(
      (__attribute__((address_space(1))) void*)g,
      (__attribute__((address_space(3))) void*)l,
      16, 0, 0);
}

constexpr int S_ = 1024, D_ = 4096, HQ_ = 32, HKV_ = 8, HD_ = 128, B_ = 4;

// ---------------- convert x: fp32 -> bf16 ----------------
__global__ void conv_bf16(const float* __restrict__ in, __bf16* __restrict__ out, int n) {
  int i = (blockIdx.x * 256 + threadIdx.x) * 8;
  if (i >= n) return;
  float4 a = *(const float4*)(in + i);
  float4 b = *(const float4*)(in + i + 4);
  bf16x8 o;
  o[0] = (__bf16)a.x; o[1] = (__bf16)a.y; o[2] = (__bf16)a.z; o[3] = (__bf16)a.w;
  o[4] = (__bf16)b.x; o[5] = (__bf16)b.y; o[6] = (__bf16)b.z; o[7] = (__bf16)b.w;
  *(bf16x8*)(out + i) = o;
}

// ---------------- transpose+convert weights: W[K][N] fp32 -> WT[N][K] bf16 ----------------
__global__ void conv_transpose(const float* __restrict__ W, __bf16* __restrict__ WT, int K, int N) {
  __shared__ float tile[32][33];
  int n0 = blockIdx.x * 32, k0 = blockIdx.y * 32;
  int tx = threadIdx.x & 31, ty = threadIdx.x >> 5;
#pragma unroll
  for (int i = 0; i < 32; i += 8)
    tile[ty + i][tx] = W[(size_t)(k0 + ty + i) * N + n0 + tx];
  __syncthreads();
#pragma unroll
  for (int i = 0; i < 32; i += 8)
    WT[(size_t)(n0 + ty + i) * K + k0 + tx] = (__bf16)tile[tx][ty + i];
}

// ======== 256x256 phase-interleaved GEMM (T2+T3+T4+T5), BK=64, 8 waves ========
// C = A(MxK,bf16) * BT(NxK,bf16)^T + bias.
// LDS: 2 buffers x { A0,A1,B0,B1 sub-tiles of 128x64 } = 128 KB.
// Sub-tile <-> quadrant alignment: A_sub mq holds rows {wm*128 + mq*64 .. +63} for both wm;
// B_sub nq holds rows {wn*64 + nq*32 .. +31} for all wn.
// XOR swizzle: phys_chunk = logical_chunk ^ (subrow & 7)  (conflict-free ds_read_b128,
// linear LDS dest for global_load_lds with pre-swizzled global source column).
// Phases per K-tile v (stage targets tile v+1):
//  p0: stage A0' | vmcnt(6) | bar | read A0(mq0),B0(nq0) | MFMA quad(0,0)
//  p1: stage B0' | vmcnt(6) | bar | read B1(nq1)         | MFMA quad(0,1)
//  p2: stage B1' | vmcnt(6) | bar | read A1(mq1)         | MFMA quad(1,1)
//  p3: stage A1' |          | bar | read B0(nq0)         | MFMA quad(1,0)
// Tail tile: no stage, vmcnt 4/2/0.
// MODE 0: fp32 out [M][N] + b0.  MODE 1: fused QKV epilogue (q/k/v^T split).
template<int MODE>
__global__ __launch_bounds__(512, 2)
void gemm8p(const __bf16* __restrict__ A, const __bf16* __restrict__ BT,
            const float* __restrict__ b0, const float* __restrict__ b1,
            const float* __restrict__ b2, void* __restrict__ Cout,
            int M, int N, int K)
{
  __shared__ __bf16 lds[65536];  // 128 KB: 2 x 32768 elems
  const int t = threadIdx.x;
  const int lane = t & 63, w = t >> 6;
  const int wm = w >> 2, wn = w & 3;
  const int g = (lane >> 4) & 3, c = lane & 15;

  // XCD-aware bijective swizzle (nwg % 8 == 0 for all our launches)
  const int gridX = gridDim.x;
  const int nwg = gridDim.x * gridDim.y;
  int lin = blockIdx.y * gridDim.x + blockIdx.x;
  lin = (lin & 7) * (nwg >> 3) + (lin >> 3);
  const int bx = lin % gridX, by = lin / gridX;
  const int m0 = by * 256, n0 = bx * 256;

  const floatx4 zero4 = {0.f, 0.f, 0.f, 0.f};
  floatx4 acc[2][2][4][2];  // [mq][nq][i][j]
#pragma unroll
  for (int a = 0; a < 2; a++)
#pragma unroll
    for (int bq = 0; bq < 2; bq++)
#pragma unroll
      for (int i = 0; i < 4; i++)
#pragma unroll
        for (int j = 0; j < 2; j++) acc[a][bq][i][j] = zero4;

  // ---- staging constants (thread t stages chunk t and t+512 of each sub-tile)
  const int t3 = t >> 3;
  const int l8 = ((t & 7) ^ (t3 & 7)) * 8;       // pre-swizzled logical chunk
  const int browc = (t3 & 31) + ((t3 >> 5) << 6);
  const __bf16* srcA0 = A  + (size_t)(m0 + t3) * K + l8;
  const __bf16* srcA1 = A  + (size_t)(m0 + 64 + t3) * K + l8;
  const __bf16* srcB0 = BT + (size_t)(n0 + browc) * K + l8;
  const __bf16* srcB1 = BT + (size_t)(n0 + 32 + browc) * K + l8;
  const size_t k128 = (size_t)128 * K;

  // ---- read constants
  const int arow_rd = (wm * 64 + c) * 64;
  const int brow_rd = (wn * 32 + c) * 64;
  const int sel0 = ((g) ^ (c & 7)) * 8;
  const int sel1 = ((4 + g) ^ (c & 7)) * 8;

  const int NT = K >> 6;

#define STG(srcp, subofs, kt, pbuf)                                              \
  gload16((srcp) + (size_t)(kt) * 64,        &lds[(pbuf) + (subofs) + t * 8]);   \
  gload16((srcp) + (size_t)(kt) * 64 + k128, &lds[(pbuf) + (subofs) + 4096 + t * 8]);

#define LOADA(MQ, bb)                                                            \
  _Pragma("unroll")                                                              \
  for (int i = 0; i < 4; i++) {                                                  \
    af[i][0] = *(const bf16x8*)&lds[(bb) + (MQ)*8192 + arow_rd + i*1024 + sel0]; \
    af[i][1] = *(const bf16x8*)&lds[(bb) + (MQ)*8192 + arow_rd + i*1024 + sel1]; \
  }

#define LOADB(NQ, bb)                                                            \
  _Pragma("unroll")                                                              \
  for (int j = 0; j < 2; j++) {                                                  \
    bf[j][0] = *(const bf16x8*)&lds[(bb) + 16384 + (NQ)*8192 + brow_rd + j*1024 + sel0]; \
    bf[j][1] = *(const bf16x8*)&lds[(bb) + 16384 + (NQ)*8192 + brow_rd + j*1024 + sel1]; \
  }

#define MFMAQ(MQ, NQ)                                                            \
  __builtin_amdgcn_s_setprio(1);                                                 \
  _Pragma("unroll")                                                              \
  for (int i = 0; i < 4; i++)                                                    \
    _Pragma("unroll")                                                            \
    for (int j = 0; j < 2; j++) {                                                \
      acc[MQ][NQ][i][j] = __builtin_amdgcn_mfma_f32_16x16x32_bf16(af[i][0], bf[j][0], acc[MQ][NQ][i][j], 0, 0, 0); \
      acc[MQ][NQ][i][j] = __builtin_amdgcn_mfma_f32_16x16x32_bf16(af[i][1], bf[j][1], acc[MQ][NQ][i][j], 0, 0, 0); \
    }                                                                            \
  __builtin_amdgcn_s_setprio(0);                                                 \
  __builtin_amdgcn_sched_barrier(0);

#define BAR()                                                                    \
  __builtin_amdgcn_sched_barrier(0);                                             \
  __builtin_amdgcn_s_barrier();                                                  \
  __builtin_amdgcn_sched_barrier(0);

#define VMC(N) asm volatile("s_waitcnt vmcnt(" #N ")" ::: "memory");

#define TILE(v, DOSTAGE, VM0, VM1, VM2) {                                        \
  const int bb = ((v) & 1) * 32768;                                              \
  const int nb = bb ^ 32768;                                                     \
  bf16x8 af[4][2], bf[2][2];                                                     \
  /* p0 */                                                                       \
  if (DOSTAGE) { STG(srcA0, 0, (v) + 1, nb) }                                    \
  VMC(VM0) BAR()                                                                 \
  LOADA(0, bb) LOADB(0, bb)                                                      \
  MFMAQ(0, 0)                                                                    \
  /* p1 */                                                                       \
  if (DOSTAGE) { STG(srcB0, 16384, (v) + 1, nb) }                                \
  VMC(VM1) BAR()                                                                 \
  LOADB(1, bb)                                                                   \
  MFMAQ(0, 1)                                                                    \
  /* p2 */                                                                       \
  if (DOSTAGE) { STG(srcB1, 24576, (v) + 1, nb) }                                \
  VMC(VM2) BAR()                                                                 \
  LOADA(1, bb)                                                                   \
  MFMAQ(1, 1)                                                                    \
  /* p3 */                                                                       \
  if (DOSTAGE) { STG(srcA1, 8192, (v) + 1, nb) }                                 \
  BAR()                                                                          \
  LOADB(0, bb)                                                                   \
  MFMAQ(1, 0)                                                                    \
}

  // prologue: tile 0 into buf0, issue order A0,B0,B1,A1 (matches per-phase order)
  STG(srcA0, 0, 0, 0)
  STG(srcB0, 16384, 0, 0)
  STG(srcB1, 24576, 0, 0)
  STG(srcA1, 8192, 0, 0)

  for (int v = 0; v < NT - 1; ++v) {
    TILE(v, true, 6, 6, 6)
  }
  TILE(NT - 1, false, 4, 2, 0)

#undef STG
#undef LOADA
#undef LOADB
#undef MFMAQ
#undef BAR
#undef VMC
#undef TILE

  // ---- epilogue
#pragma unroll
  for (int mq = 0; mq < 2; mq++)
#pragma unroll
    for (int nq = 0; nq < 2; nq++)
#pragma unroll
      for (int j = 0; j < 2; j++) {
        const int ncol = n0 + wn * 64 + nq * 32 + j * 16 + c;
#pragma unroll
        for (int i = 0; i < 4; i++) {
          const int mbase = m0 + wm * 128 + mq * 64 + i * 16 + g * 4;
#pragma unroll
          for (int r = 0; r < 4; r++) {
            const int m = mbase + r;
            float v = acc[mq][nq][i][j][r];
            if constexpr (MODE == 0) {
              ((float*)Cout)[(size_t)m * N + ncol] = v + b0[ncol];
            } else {
              const int bb2 = m >> 10, s = m & 1023;
              __bf16* qkv = (__bf16*)Cout;
              if (ncol < 4096) {
                v += b0[ncol];
                const int h = ncol >> 7, d = ncol & 127;
                qkv[(((size_t)bb2 * 32 + h) * 1024 + s) * 128 + d] = (__bf16)v;
              } else if (ncol < 5120) {
                const int nc = ncol - 4096;
                v += b1[nc];
                const int h = nc >> 7, d = nc & 127;
                qkv[16777216 + (((size_t)bb2 * 8 + h) * 1024 + s) * 128 + d] = (__bf16)v;
              } else {
                const int nc = ncol - 5120;
                v += b2[nc];
                const int h = nc >> 7, d = nc & 127;
                qkv[20971520 + (((size_t)bb2 * 8 + h) * 128 + d) * 1024 + s] = (__bf16)v;
              }
            }
          }
        }
      }
}

// ---------------- RoPE in-place on q_t (b,h,s,d) and k_t ----------------
constexpr int NQCH = B_ * HQ_ * S_ * (HD_ / 8);
constexpr int NKCH = B_ * HKV_ * S_ * (HD_ / 8);
__global__ void rope_kernel(__bf16* __restrict__ qt, __bf16* __restrict__ kt,
                            const float* __restrict__ fc, const int* __restrict__ sp) {
  int tid = blockIdx.x * 256 + threadIdx.x;
  __bf16* p;
  int idx;
  if (tid < NQCH) { p = qt; idx = tid; }
  else { idx = tid - NQCH; if (idx >= NKCH) return; p = kt; }
  const int c8 = idx & 15;
  const int s  = (idx >> 4) & 1023;
  const int srow = sp[0] + s;
  const float* f = fc + (size_t)srow * 128 + c8 * 8;
  float4 fa = *(const float4*)(f);
  float4 fb = *(const float4*)(f + 4);
  __bf16* q = p + (size_t)idx * 8;
  bf16x8 v = *(const bf16x8*)q;
  float a0 = (float)v[0], b0 = (float)v[1], a1 = (float)v[2], b1 = (float)v[3];
  float a2 = (float)v[4], b2 = (float)v[5], a3 = (float)v[6], b3 = (float)v[7];
  bf16x8 o;
  o[0] = (__bf16)(a0 * fa.x - b0 * fa.y); o[1] = (__bf16)(a0 * fa.y + b0 * fa.x);
  o[2] = (__bf16)(a1 * fa.z - b1 * fa.w); o[3] = (__bf16)(a1 * fa.w + b1 * fa.z);
  o[4] = (__bf16)(a2 * fb.x - b2 * fb.y); o[5] = (__bf16)(a2 * fb.y + b2 * fb.x);
  o[6] = (__bf16)(a3 * fb.z - b3 * fb.w); o[7] = (__bf16)(a3 * fb.w + b3 * fb.z);
  *(bf16x8*)q = o;
}

// ---------------- flash attention: swapped-QK^T 32x32, in-register softmax ----------------
__global__ __launch_bounds__(256, 2)
void flash_attn(const __bf16* __restrict__ qt, const __bf16* __restrict__ kt,
                const __bf16* __restrict__ vt, __bf16* __restrict__ obuf)
{
  const int lane = threadIdx.x & 63, w = threadIdx.x >> 6;
  const int rl = lane & 31, hi = lane >> 5;
  const int qb = blockIdx.x & 7;
  const int bh = blockIdx.x >> 3;
  const int b = bh >> 5, h = bh & 31, hk = h >> 2;
  const int q0w = (qb + w * 8) * 32;

  const __bf16* Qp = qt + (size_t)(b * HQ_ + h) * S_ * HD_;
  const __bf16* Kp = kt + (size_t)(b * HKV_ + hk) * S_ * HD_;
  const __bf16* Vp = vt + (size_t)(b * HKV_ + hk) * HD_ * S_;  // V^T [d][s]

  const __bf16* Qb = Qp + (size_t)(q0w + rl) * HD_ + hi * 8;
  bf16x8 qf[8];
#pragma unroll
  for (int d = 0; d < 8; d++) qf[d] = *(const bf16x8*)(Qb + d * 16);

  const __bf16* Kb = Kp + (size_t)rl * HD_ + hi * 8;
  const __bf16* Vb = Vp + (size_t)rl * S_ + hi * 8;

  const floatx16 zero16 = {0.f,0.f,0.f,0.f,0.f,0.f,0.f,0.f,0.f,0.f,0.f,0.f,0.f,0.f,0.f,0.f};
  floatx16 oacc[4];
#pragma unroll
  for (int dt = 0; dt < 4; dt++) oacc[dt] = zero16;

  float m_run = -__builtin_inff();
  float l_run = 0.f;
  const float ksc = 0.12751744875895f;  // (1/sqrt(128)) * log2(e)

  for (int kv0 = 0; kv0 <= q0w; kv0 += 32) {
    floatx16 acc = zero16;
    bf16x8 kf[8];
#pragma unroll
    for (int d = 0; d < 8; d++)
      kf[d] = *(const bf16x8*)(Kb + (size_t)kv0 * HD_ + d * 16);
#pragma unroll
    for (int d = 0; d < 8; d++)
      acc = __builtin_amdgcn_mfma_f32_32x32x16_bf16(kf[d], qf[d], acc, 0, 0, 0);

    bf16x8 vf[4][2];
#pragma unroll
    for (int dt = 0; dt < 4; dt++)
#pragma unroll
      for (int kh = 0; kh < 2; kh++)
        vf[dt][kh] = *(const bf16x8*)(Vb + (size_t)dt * 32 * S_ + kv0 + kh * 16);

    if (kv0 == q0w) {
#pragma unroll
      for (int r = 0; r < 16; r++) {
        const int krel = (r & 3) + 8 * (r >> 2) + 4 * hi;
        if (krel > rl) acc[r] = -3e29f;
      }
    }

    float mx = acc[0];
#pragma unroll
    for (int r = 1; r < 16; r++) mx = fmaxf(mx, acc[r]);
    mx = fmaxf(mx, __shfl_xor(mx, 32));
    const float m_cand = mx * ksc;

    float m_use;
    const bool defer = __all(m_cand - m_run <= 8.0f);
    if (defer) {
      m_use = m_run;
    } else {
      const float m_new = fmaxf(m_run, m_cand);
      const float alpha = exp2f(m_run - m_new);
      l_run *= alpha;
      float ar[16];
#pragma unroll
      for (int r = 0; r < 16; r++)
        ar[r] = __shfl(alpha, (r & 3) + 8 * (r >> 2) + 4 * hi);
#pragma unroll
      for (int dt = 0; dt < 4; dt++)
#pragma unroll
        for (int r = 0; r < 16; r++) oacc[dt][r] *= ar[r];
      m_run = m_new;
      m_use = m_new;
    }

    float pr[16];
#pragma unroll
    for (int r = 0; r < 16; r++) pr[r] = exp2f(fmaf(acc[r], ksc, -m_use));
    float rs = pr[0];
#pragma unroll
    for (int r = 1; r < 16; r++) rs += pr[r];
    rs += __shfl_xor(rs, 32);
    l_run += rs;

    bf16x8 pa[2];
#pragma unroll
    for (int kh = 0; kh < 2; kh++) {
      const int rb = kh * 8;
      unsigned a0, b0, a1, b1;
      asm("v_cvt_pk_bf16_f32 %0, %1, %2" : "=v"(a0) : "v"(pr[rb + 0]), "v"(pr[rb + 1]));
      asm("v_cvt_pk_bf16_f32 %0, %1, %2" : "=v"(b0) : "v"(pr[rb + 4]), "v"(pr[rb + 5]));
      asm("v_cvt_pk_bf16_f32 %0, %1, %2" : "=v"(a1) : "v"(pr[rb + 2]), "v"(pr[rb + 3]));
      asm("v_cvt_pk_bf16_f32 %0, %1, %2" : "=v"(b1) : "v"(pr[rb + 6]), "v"(pr[rb + 7]));
      asm("v_permlane32_swap_b32 %0, %1" : "+v"(a0), "+v"(b0));
      asm("v_permlane32_swap_b32 %0, %1" : "+v"(a1), "+v"(b1));
      union { unsigned u[4]; bf16x8 v; } cvt;
      cvt.u[0] = a0; cvt.u[1] = a1; cvt.u[2] = b0; cvt.u[3] = b1;
      pa[kh] = cvt.v;
    }

#pragma unroll
    for (int dt = 0; dt < 4; dt++) {
      oacc[dt] = __builtin_amdgcn_mfma_f32_32x32x16_bf16(pa[0], vf[dt][0], oacc[dt], 0, 0, 0);
      oacc[dt] = __builtin_amdgcn_mfma_f32_32x32x16_bf16(pa[1], vf[dt][1], oacc[dt], 0, 0, 0);
    }
  }

  const float linv = 1.f / l_run;
  float lr[16];
#pragma unroll
  for (int r = 0; r < 16; r++)
    lr[r] = __shfl(linv, (r & 3) + 8 * (r >> 2) + 4 * hi);
#pragma unroll
  for (int dt = 0; dt < 4; dt++)
#pragma unroll
    for (int r = 0; r < 16; r++) {
      const int qrow = q0w + (r & 3) + 8 * (r >> 2) + 4 * hi;
      const size_t o = (size_t)(b * S_ + qrow) * D_ + h * HD_ + dt * 32 + rl;
      obuf[o] = (__bf16)(oacc[dt][r] * lr[r]);
    }
}

extern "C" void kernel_launch(void* const* d_in, const int* in_sizes, int n_in,
                              void* d_out, int out_size, void* d_ws, size_t ws_size,
                              hipStream_t stream) {
  (void)in_sizes; (void)n_in; (void)out_size;
  const float* x  = (const float*)d_in[0];
  const float* fc = (const float*)d_in[1];
  const float* Wq = (const float*)d_in[2];
  const float* bq = (const float*)d_in[3];
  const float* Wk = (const float*)d_in[4];
  const float* bk = (const float*)d_in[5];
  const float* Wv = (const float*)d_in[6];
  const float* bv = (const float*)d_in[7];
  const float* Wo = (const float*)d_in[8];
  const float* bo = (const float*)d_in[9];
  const int*   sp = (const int*)d_in[10];
  float* out = (float*)d_out;

  const size_t MB = 1024 * 1024;
  if (ws_size < 192 * MB) return;
  char* ws = (char*)d_ws;
  __bf16* xb     = (__bf16*)(ws + 0);        // 32 MB
  __bf16* WqkvT  = (__bf16*)(ws + 32 * MB);  // 48 MB: Wq^T | Wk^T | Wv^T  [6144][4096]
  __bf16* WoT    = (__bf16*)(ws + 80 * MB);  // 32 MB
  __bf16* q_t    = (__bf16*)(ws + 112 * MB); // 32 MB (b,h,s,d)
  __bf16* k_t    = (__bf16*)(ws + 144 * MB); //  8 MB (b,h,s,d)
  __bf16* v_t    = (__bf16*)(ws + 152 * MB); //  8 MB (b,h,d,s)
  __bf16* ob     = (__bf16*)(ws + 160 * MB); // 32 MB

  conv_bf16<<<8192, 256, 0, stream>>>(x, xb, D_ * B_ * S_);
  conv_transpose<<<dim3(128, 128), 256, 0, stream>>>(Wq, WqkvT, 4096, 4096);
  conv_transpose<<<dim3(32, 128),  256, 0, stream>>>(Wk, WqkvT + (size_t)4096 * 4096, 4096, 1024);
  conv_transpose<<<dim3(32, 128),  256, 0, stream>>>(Wv, WqkvT + (size_t)5120 * 4096, 4096, 1024);
  conv_transpose<<<dim3(128, 128), 256, 0, stream>>>(Wo, WoT, 4096, 4096);

  // fused QKV projection: [4096 x 6144] = xb @ [Wq|Wk|Wv]
  gemm8p<1><<<dim3(24, 16), 512, 0, stream>>>(xb, WqkvT, bq, bk, bv, q_t, 4096, 6144, 4096);

  rope_kernel<<<(NQCH + NKCH) / 256, 256, 0, stream>>>(q_t, k_t, fc, sp);
  flash_attn<<<1024, 256, 0, stream>>>(q_t, k_t, v_t, ob);

  gemm8p<0><<<dim3(16, 16), 512, 0, stream>>>(ob, WoT, bo, nullptr, nullptr, out, 4096, 4096, 4096);
}

// Round 6
// 613.007 us; speedup vs baseline: 2.1343x; 1.0079x over previous
//
#include <hip/hip_runtime.h>
#include <hip/hip_bf16.h>

using bf16x8   = __attribute__((ext_vector_type(8))) __bf16;
using floatx4  = __attribute__((ext_vector_type(4))) float;
using floatx16 = __attribute__((ext_vector_type(16))) float;

#define DEVINL __device__ __forceinline__

DEVINL void gload16(const void* g, void* l) {
  __builtin_amdgcn_global_load_lds(
      (__attribute__((address_space(1))) void*)g,
      (__attribute__((address_space(3))) void*)l,
      16, 0, 0);
}

constexpr int S_ = 1024, D_ = 4096, HQ_ = 32, HKV_ = 8, HD_ = 128, B_ = 4;

// ---------------- convert x: fp32 -> bf16 ----------------
__global__ void conv_bf16(const float* __restrict__ in, __bf16* __restrict__ out, int n) {
  int i = (blockIdx.x * 256 + threadIdx.x) * 8;
  if (i >= n) return;
  float4 a = *(const float4*)(in + i);
  float4 b = *(const float4*)(in + i + 4);
  bf16x8 o;
  o[0] = (__bf16)a.x; o[1] = (__bf16)a.y; o[2] = (__bf16)a.z; o[3] = (__bf16)a.w;
  o[4] = (__bf16)b.x; o[5] = (__bf16)b.y; o[6] = (__bf16)b.z; o[7] = (__bf16)b.w;
  *(bf16x8*)(out + i) = o;
}

// ---------------- transpose+convert weights: W[K][N] fp32 -> WT[N][K] bf16 ----------------
__global__ void conv_transpose(const float* __restrict__ W, __bf16* __restrict__ WT, int K, int N) {
  __shared__ float tile[32][33];
  int n0 = blockIdx.x * 32, k0 = blockIdx.y * 32;
  int tx = threadIdx.x & 31, ty = threadIdx.x >> 5;
#pragma unroll
  for (int i = 0; i < 32; i += 8)
    tile[ty + i][tx] = W[(size_t)(k0 + ty + i) * N + n0 + tx];
  __syncthreads();
#pragma unroll
  for (int i = 0; i < 32; i += 8)
    WT[(size_t)(n0 + ty + i) * K + k0 + tx] = (__bf16)tile[tx][ty + i];
}

// ======== 256x256 m201-schedule GEMM (T2+T3+T4+T5), BK=64, 8 waves ========
// Per phase: {ds_read subtile ; stage 1 unit ; [vmcnt(4)] ; BAR ; lgkmcnt(0) ;
//             setprio(1) 16xMFMA setprio(0) ; BAR}.
// vmcnt ledger (2 loads/unit, stage order A0,B0,B1,A1 one unit/phase, 1 tile ahead):
//   steady state: vmcnt(4) at p0,p1,p3; none at p2; tail tile: 2,0,-,-.
// Reads: p0: A0(8)+B0(4); p1: B1(4); p2: A1(8, overwrites af); p3: none (reuse bf0/af).
template<int MODE>
__global__ __launch_bounds__(512, 1)
void gemm8p(const __bf16* __restrict__ A, const __bf16* __restrict__ BT,
            const float* __restrict__ b0, const float* __restrict__ b1,
            const float* __restrict__ b2, void* __restrict__ Cout,
            int M, int N, int K)
{
  __shared__ __bf16 lds[65536];  // 128 KB: 2 x 32768 elems
  const int t = threadIdx.x;
  const int lane = t & 63, w = t >> 6;
  const int wm = w >> 2, wn = w & 3;
  const int g = (lane >> 4) & 3, c = lane & 15;

  const int gridX = gridDim.x;
  const int nwg = gridDim.x * gridDim.y;
  int lin = blockIdx.y * gridDim.x + blockIdx.x;
  lin = (lin & 7) * (nwg >> 3) + (lin >> 3);
  const int bx = lin % gridX, by = lin / gridX;
  const int m0 = by * 256, n0 = bx * 256;

  const floatx4 zero4 = {0.f, 0.f, 0.f, 0.f};
  floatx4 acc[2][2][4][2];  // [mq][nq][i][j]
#pragma unroll
  for (int a = 0; a < 2; a++)
#pragma unroll
    for (int bq = 0; bq < 2; bq++)
#pragma unroll
      for (int i = 0; i < 4; i++)
#pragma unroll
        for (int j = 0; j < 2; j++) acc[a][bq][i][j] = zero4;

  // ---- staging constants (identical to verified round-5 layout)
  const int t3 = t >> 3;
  const int l8 = ((t & 7) ^ (t3 & 7)) * 8;
  const int browc = (t3 & 31) + ((t3 >> 5) << 6);
  const __bf16* srcA0 = A  + (size_t)(m0 + t3) * K + l8;
  const __bf16* srcA1 = A  + (size_t)(m0 + 64 + t3) * K + l8;
  const __bf16* srcB0 = BT + (size_t)(n0 + browc) * K + l8;
  const __bf16* srcB1 = BT + (size_t)(n0 + 32 + browc) * K + l8;
  const size_t k128 = (size_t)128 * K;

  // ---- read constants
  const int arow_rd = (wm * 64 + c) * 64;
  const int brow_rd = (wn * 32 + c) * 64;
  const int sel0 = ((g) ^ (c & 7)) * 8;
  const int sel1 = ((4 + g) ^ (c & 7)) * 8;

  const int NT = K >> 6;

  bf16x8 af[4][2], bf0[2][2], bf1[2][2];

#define STG(srcp, subofs, kt, pbuf)                                              \
  gload16((srcp) + (size_t)(kt) * 64,        &lds[(pbuf) + (subofs) + t * 8]);   \
  gload16((srcp) + (size_t)(kt) * 64 + k128, &lds[(pbuf) + (subofs) + 4096 + t * 8]);

#define LOADA(MQ, bb)                                                            \
  _Pragma("unroll")                                                              \
  for (int i = 0; i < 4; i++) {                                                  \
    af[i][0] = *(const bf16x8*)&lds[(bb) + (MQ)*8192 + arow_rd + i*1024 + sel0]; \
    af[i][1] = *(const bf16x8*)&lds[(bb) + (MQ)*8192 + arow_rd + i*1024 + sel1]; \
  }

#define LOADB(DST, NQ, bb)                                                       \
  _Pragma("unroll")                                                              \
  for (int j = 0; j < 2; j++) {                                                  \
    DST[j][0] = *(const bf16x8*)&lds[(bb) + 16384 + (NQ)*8192 + brow_rd + j*1024 + sel0]; \
    DST[j][1] = *(const bf16x8*)&lds[(bb) + 16384 + (NQ)*8192 + brow_rd + j*1024 + sel1]; \
  }

#define MFMAQ(MQ, NQ, BF)                                                        \
  __builtin_amdgcn_s_setprio(1);                                                 \
  _Pragma("unroll")                                                              \
  for (int i = 0; i < 4; i++)                                                    \
    _Pragma("unroll")                                                            \
    for (int j = 0; j < 2; j++) {                                                \
      acc[MQ][NQ][i][j] = __builtin_amdgcn_mfma_f32_16x16x32_bf16(af[i][0], BF[j][0], acc[MQ][NQ][i][j], 0, 0, 0); \
      acc[MQ][NQ][i][j] = __builtin_amdgcn_mfma_f32_16x16x32_bf16(af[i][1], BF[j][1], acc[MQ][NQ][i][j], 0, 0, 0); \
    }                                                                            \
  __builtin_amdgcn_s_setprio(0);

#define SBAR() __builtin_amdgcn_sched_barrier(0)
#define BARR() __builtin_amdgcn_s_barrier()
#define VMC(N) asm volatile("s_waitcnt vmcnt(" #N ")" ::: "memory");
#define LGKM0() asm volatile("s_waitcnt lgkmcnt(0)" ::: "memory");

  // prologue: stage tile 0 (units A0,B0,B1,A1), guarantee A0+B0 before first reads
  STG(srcA0, 0, 0, 0)
  STG(srcB0, 16384, 0, 0)
  STG(srcB1, 24576, 0, 0)
  STG(srcA1, 8192, 0, 0)
  VMC(4) BARR(); SBAR();

  for (int v = 0; v < NT - 1; ++v) {
    const int bb = (v & 1) * 32768;
    const int nb = bb ^ 32768;
    // ---- p0: read A0,B0 | stage A0' | vmcnt(4) (covers p1's B1)
    LOADA(0, bb)
    LOADB(bf0, 0, bb)
    STG(srcA0, 0, v + 1, nb)
    SBAR(); VMC(4) BARR(); LGKM0() SBAR();
    MFMAQ(0, 0, bf0)
    SBAR(); BARR(); SBAR();
    // ---- p1: read B1 | stage B0' | vmcnt(4) (covers p2's A1)
    LOADB(bf1, 1, bb)
    STG(srcB0, 16384, v + 1, nb)
    SBAR(); VMC(4) BARR(); LGKM0() SBAR();
    MFMAQ(0, 1, bf1)
    SBAR(); BARR(); SBAR();
    // ---- p2: read A1 | stage B1' | no vmcnt
    LOADA(1, bb)
    STG(srcB1, 24576, v + 1, nb)
    SBAR(); BARR(); LGKM0() SBAR();
    MFMAQ(1, 1, bf1)
    SBAR(); BARR(); SBAR();
    // ---- p3: no reads | stage A1' | vmcnt(4) (covers next tile p0's A0,B0)
    STG(srcA1, 8192, v + 1, nb)
    SBAR(); VMC(4) BARR(); SBAR();
    MFMAQ(1, 0, bf0)
    SBAR(); BARR(); SBAR();
  }
  {
    // tail tile NT-1 (no staging): vmcnt 2 / 0
    const int bb = ((NT - 1) & 1) * 32768;
    LOADA(0, bb)
    LOADB(bf0, 0, bb)
    SBAR(); VMC(2) BARR(); LGKM0() SBAR();
    MFMAQ(0, 0, bf0)
    SBAR(); BARR(); SBAR();
    LOADB(bf1, 1, bb)
    SBAR(); VMC(0) BARR(); LGKM0() SBAR();
    MFMAQ(0, 1, bf1)
    SBAR(); BARR(); SBAR();
    LOADA(1, bb)
    SBAR(); BARR(); LGKM0() SBAR();
    MFMAQ(1, 1, bf1)
    MFMAQ(1, 0, bf0)
  }

#undef STG
#undef LOADA
#undef LOADB
#undef MFMAQ
#undef SBAR
#undef BARR
#undef VMC
#undef LGKM0

  // ---- epilogue
#pragma unroll
  for (int mq = 0; mq < 2; mq++)
#pragma unroll
    for (int nq = 0; nq < 2; nq++)
#pragma unroll
      for (int j = 0; j < 2; j++) {
        const int ncol = n0 + wn * 64 + nq * 32 + j * 16 + c;
#pragma unroll
        for (int i = 0; i < 4; i++) {
          const int mbase = m0 + wm * 128 + mq * 64 + i * 16 + g * 4;
#pragma unroll
          for (int r = 0; r < 4; r++) {
            const int m = mbase + r;
            float v = acc[mq][nq][i][j][r];
            if constexpr (MODE == 0) {
              ((float*)Cout)[(size_t)m * N + ncol] = v + b0[ncol];
            } else {
              const int bb2 = m >> 10, s = m & 1023;
              __bf16* qkv = (__bf16*)Cout;
              if (ncol < 4096) {
                v += b0[ncol];
                const int h = ncol >> 7, d = ncol & 127;
                qkv[(((size_t)bb2 * 32 + h) * 1024 + s) * 128 + d] = (__bf16)v;
              } else if (ncol < 5120) {
                const int nc = ncol - 4096;
                v += b1[nc];
                const int h = nc >> 7, d = nc & 127;
                qkv[16777216 + (((size_t)bb2 * 8 + h) * 1024 + s) * 128 + d] = (__bf16)v;
              } else {
                const int nc = ncol - 5120;
                v += b2[nc];
                const int h = nc >> 7, d = nc & 127;
                qkv[20971520 + (((size_t)bb2 * 8 + h) * 128 + d) * 1024 + s] = (__bf16)v;
              }
            }
          }
        }
      }
}

// ---------------- RoPE in-place on q_t (b,h,s,d) and k_t ----------------
constexpr int NQCH = B_ * HQ_ * S_ * (HD_ / 8);
constexpr int NKCH = B_ * HKV_ * S_ * (HD_ / 8);
__global__ void rope_kernel(__bf16* __restrict__ qt, __bf16* __restrict__ kt,
                            const float* __restrict__ fc, const int* __restrict__ sp) {
  int tid = blockIdx.x * 256 + threadIdx.x;
  __bf16* p;
  int idx;
  if (tid < NQCH) { p = qt; idx = tid; }
  else { idx = tid - NQCH; if (idx >= NKCH) return; p = kt; }
  const int c8 = idx & 15;
  const int s  = (idx >> 4) & 1023;
  const int srow = sp[0] + s;
  const float* f = fc + (size_t)srow * 128 + c8 * 8;
  float4 fa = *(const float4*)(f);
  float4 fb = *(const float4*)(f + 4);
  __bf16* q = p + (size_t)idx * 8;
  bf16x8 v = *(const bf16x8*)q;
  float a0 = (float)v[0], b0 = (float)v[1], a1 = (float)v[2], b1 = (float)v[3];
  float a2 = (float)v[4], b2 = (float)v[5], a3 = (float)v[6], b3 = (float)v[7];
  bf16x8 o;
  o[0] = (__bf16)(a0 * fa.x - b0 * fa.y); o[1] = (__bf16)(a0 * fa.y + b0 * fa.x);
  o[2] = (__bf16)(a1 * fa.z - b1 * fa.w); o[3] = (__bf16)(a1 * fa.w + b1 * fa.z);
  o[4] = (__bf16)(a2 * fb.x - b2 * fb.y); o[5] = (__bf16)(a2 * fb.y + b2 * fb.x);
  o[6] = (__bf16)(a3 * fb.z - b3 * fb.w); o[7] = (__bf16)(a3 * fb.w + b3 * fb.z);
  *(bf16x8*)q = o;
}

// ---------------- flash attention: swapped-QK^T 32x32, in-register softmax ----------------
__global__ __launch_bounds__(256, 2)
void flash_attn(const __bf16* __restrict__ qt, const __bf16* __restrict__ kt,
                const __bf16* __restrict__ vt, __bf16* __restrict__ obuf)
{
  const int lane = threadIdx.x & 63, w = threadIdx.x >> 6;
  const int rl = lane & 31, hi = lane >> 5;
  const int qb = blockIdx.x & 7;
  const int bh = blockIdx.x >> 3;
  const int b = bh >> 5, h = bh & 31, hk = h >> 2;
  const int q0w = (qb + w * 8) * 32;

  const __bf16* Qp = qt + (size_t)(b * HQ_ + h) * S_ * HD_;
  const __bf16* Kp = kt + (size_t)(b * HKV_ + hk) * S_ * HD_;
  const __bf16* Vp = vt + (size_t)(b * HKV_ + hk) * HD_ * S_;  // V^T [d][s]

  const __bf16* Qb = Qp + (size_t)(q0w + rl) * HD_ + hi * 8;
  bf16x8 qf[8];
#pragma unroll
  for (int d = 0; d < 8; d++) qf[d] = *(const bf16x8*)(Qb + d * 16);

  const __bf16* Kb = Kp + (size_t)rl * HD_ + hi * 8;
  const __bf16* Vb = Vp + (size_t)rl * S_ + hi * 8;

  const floatx16 zero16 = {0.f,0.f,0.f,0.f,0.f,0.f,0.f,0.f,0.f,0.f,0.f,0.f,0.f,0.f,0.f,0.f};
  floatx16 oacc[4];
#pragma unroll
  for (int dt = 0; dt < 4; dt++) oacc[dt] = zero16;

  float m_run = -__builtin_inff();
  float l_run = 0.f;
  const float ksc = 0.12751744875895f;  // (1/sqrt(128)) * log2(e)

  for (int kv0 = 0; kv0 <= q0w; kv0 += 32) {
    floatx16 acc = zero16;
    bf16x8 kf[8];
#pragma unroll
    for (int d = 0; d < 8; d++)
      kf[d] = *(const bf16x8*)(Kb + (size_t)kv0 * HD_ + d * 16);
#pragma unroll
    for (int d = 0; d < 8; d++)
      acc = __builtin_amdgcn_mfma_f32_32x32x16_bf16(kf[d], qf[d], acc, 0, 0, 0);

    bf16x8 vf[4][2];
#pragma unroll
    for (int dt = 0; dt < 4; dt++)
#pragma unroll
      for (int kh = 0; kh < 2; kh++)
        vf[dt][kh] = *(const bf16x8*)(Vb + (size_t)dt * 32 * S_ + kv0 + kh * 16);

    if (kv0 == q0w) {
#pragma unroll
      for (int r = 0; r < 16; r++) {
        const int krel = (r & 3) + 8 * (r >> 2) + 4 * hi;
        if (krel > rl) acc[r] = -3e29f;
      }
    }

    float mx = acc[0];
#pragma unroll
    for (int r = 1; r < 16; r++) mx = fmaxf(mx, acc[r]);
    mx = fmaxf(mx, __shfl_xor(mx, 32));
    const float m_cand = mx * ksc;

    float m_use;
    const bool defer = __all(m_cand - m_run <= 8.0f);
    if (defer) {
      m_use = m_run;
    } else {
      const float m_new = fmaxf(m_run, m_cand);
      const float alpha = exp2f(m_run - m_new);
      l_run *= alpha;
      float ar[16];
#pragma unroll
      for (int r = 0; r < 16; r++)
        ar[r] = __shfl(alpha, (r & 3) + 8 * (r >> 2) + 4 * hi);
#pragma unroll
      for (int dt = 0; dt < 4; dt++)
#pragma unroll
        for (int r = 0; r < 16; r++) oacc[dt][r] *= ar[r];
      m_run = m_new;
      m_use = m_new;
    }

    float pr[16];
#pragma unroll
    for (int r = 0; r < 16; r++) pr[r] = exp2f(fmaf(acc[r], ksc, -m_use));
    float rs = pr[0];
#pragma unroll
    for (int r = 1; r < 16; r++) rs += pr[r];
    rs += __shfl_xor(rs, 32);
    l_run += rs;

    bf16x8 pa[2];
#pragma unroll
    for (int kh = 0; kh < 2; kh++) {
      const int rb = kh * 8;
      unsigned a0, b0, a1, b1;
      asm("v_cvt_pk_bf16_f32 %0, %1, %2" : "=v"(a0) : "v"(pr[rb + 0]), "v"(pr[rb + 1]));
      asm("v_cvt_pk_bf16_f32 %0, %1, %2" : "=v"(b0) : "v"(pr[rb + 4]), "v"(pr[rb + 5]));
      asm("v_cvt_pk_bf16_f32 %0, %1, %2" : "=v"(a1) : "v"(pr[rb + 2]), "v"(pr[rb + 3]));
      asm("v_cvt_pk_bf16_f32 %0, %1, %2" : "=v"(b1) : "v"(pr[rb + 6]), "v"(pr[rb + 7]));
      asm("v_permlane32_swap_b32 %0, %1" : "+v"(a0), "+v"(b0));
      asm("v_permlane32_swap_b32 %0, %1" : "+v"(a1), "+v"(b1));
      union { unsigned u[4]; bf16x8 v; } cvt;
      cvt.u[0] = a0; cvt.u[1] = a1; cvt.u[2] = b0; cvt.u[3] = b1;
      pa[kh] = cvt.v;
    }

#pragma unroll
    for (int dt = 0; dt < 4; dt++) {
      oacc[dt] = __builtin_amdgcn_mfma_f32_32x32x16_bf16(pa[0], vf[dt][0], oacc[dt], 0, 0, 0);
      oacc[dt] = __builtin_amdgcn_mfma_f32_32x32x16_bf16(pa[1], vf[dt][1], oacc[dt], 0, 0, 0);
    }
  }

  const float linv = 1.f / l_run;
  float lr[16];
#pragma unroll
  for (int r = 0; r < 16; r++)
    lr[r] = __shfl(linv, (r & 3) + 8 * (r >> 2) + 4 * hi);
#pragma unroll
  for (int dt = 0; dt < 4; dt++)
#pragma unroll
    for (int r = 0; r < 16; r++) {
      const int qrow = q0w + (r & 3) + 8 * (r >> 2) + 4 * hi;
      const size_t o = (size_t)(b * S_ + qrow) * D_ + h * HD_ + dt * 32 + rl;
      obuf[o] = (__bf16)(oacc[dt][r] * lr[r]);
    }
}

extern "C" void kernel_launch(void* const* d_in, const int* in_sizes, int n_in,
                              void* d_out, int out_size, void* d_ws, size_t ws_size,
                              hipStream_t stream) {
  (void)in_sizes; (void)n_in; (void)out_size;
  const float* x  = (const float*)d_in[0];
  const float* fc = (const float*)d_in[1];
  const float* Wq = (const float*)d_in[2];
  const float* bq = (const float*)d_in[3];
  const float* Wk = (const float*)d_in[4];
  const float* bk = (const float*)d_in[5];
  const float* Wv = (const float*)d_in[6];
  const float* bv = (const float*)d_in[7];
  const float* Wo = (const float*)d_in[8];
  const float* bo = (const float*)d_in[9];
  const int*   sp = (const int*)d_in[10];
  float* out = (float*)d_out;

  const size_t MB = 1024 * 1024;
  if (ws_size < 192 * MB) return;
  char* ws = (char*)d_ws;
  __bf16* xb     = (__bf16*)(ws + 0);        // 32 MB
  __bf16* WqkvT  = (__bf16*)(ws + 32 * MB);  // 48 MB: Wq^T | Wk^T | Wv^T  [6144][4096]
  __bf16* WoT    = (__bf16*)(ws + 80 * MB);  // 32 MB
  __bf16* q_t    = (__bf16*)(ws + 112 * MB); // 32 MB (b,h,s,d)
  __bf16* k_t    = (__bf16*)(ws + 144 * MB); //  8 MB (b,h,s,d)
  __bf16* v_t    = (__bf16*)(ws + 152 * MB); //  8 MB (b,h,d,s)
  __bf16* ob     = (__bf16*)(ws + 160 * MB); // 32 MB

  conv_bf16<<<8192, 256, 0, stream>>>(x, xb, D_ * B_ * S_);
  conv_transpose<<<dim3(128, 128), 256, 0, stream>>>(Wq, WqkvT, 4096, 4096);
  conv_transpose<<<dim3(32, 128),  256, 0, stream>>>(Wk, WqkvT + (size_t)4096 * 4096, 4096, 1024);
  conv_transpose<<<dim3(32, 128),  256, 0, stream>>>(Wv, WqkvT + (size_t)5120 * 4096, 4096, 1024);
  conv_transpose<<<dim3(128, 128), 256, 0, stream>>>(Wo, WoT, 4096, 4096);

  // fused QKV projection: [4096 x 6144] = xb @ [Wq|Wk|Wv]
  gemm8p<1><<<dim3(24, 16), 512, 0, stream>>>(xb, WqkvT, bq, bk, bv, q_t, 4096, 6144, 4096);

  rope_kernel<<<(NQCH + NKCH) / 256, 256, 0, stream>>>(q_t, k_t, fc, sp);
  flash_attn<<<1024, 256, 0, stream>>>(q_t, k_t, v_t, ob);

  gemm8p<0><<<dim3(16, 16), 512, 0, stream>>>(ob, WoT, bo, nullptr, nullptr, out, 4096, 4096, 4096);
}